// Round 1
// baseline (11212.812 us; speedup 1.0000x reference)
//
#include <hip/hip_runtime.h>
#include <math.h>

#define SEQ    2048
#define EMBED  1280
#define HEADS  16
#define HD     80
#define MLP    5120
#define HIDDEN 3584
#define QKVN   3840   // 3*EMBED
#define SEGLEN 1024
#define NSEG   2
#define PATCH_IN 1176
#define MROWS  512    // SEQ/4 merged rows

// ---------------------------------------------------------------------------
// Generic f32 GEMM: C = epi(A@B + bias) (+ C if ACC). 64x64 tile, BK=32.
// EPI: 0=none, 1=silu, 2=gelu(exact). M,N multiples of 64; K arbitrary.
// ---------------------------------------------------------------------------
template<int EPI, int ACC>
__global__ __launch_bounds__(256) void gemm_f32(
    const float* __restrict__ A, const float* __restrict__ B,
    const float* __restrict__ bias, float* __restrict__ C,
    int M, int N, int K)
{
    __shared__ float As[64][33];
    __shared__ float Bs[32][65];
    const int tx = threadIdx.x, ty = threadIdx.y;      // 16x16
    const int tid = ty * 16 + tx;
    const int row0 = blockIdx.y * 64, col0 = blockIdx.x * 64;

    float acc[4][4] = {};

    for (int k0 = 0; k0 < K; k0 += 32) {
        // A tile: 64 rows x 32 k
        #pragma unroll
        for (int t = 0; t < 8; ++t) {
            int e = tid + t * 256;
            int r = e >> 5, c = e & 31;
            int gk = k0 + c;
            As[r][c] = (gk < K) ? A[(size_t)(row0 + r) * K + gk] : 0.f;
        }
        // B tile: 32 k x 64 cols
        #pragma unroll
        for (int t = 0; t < 8; ++t) {
            int e = tid + t * 256;
            int r = e >> 6, c = e & 63;
            int gk = k0 + r;
            Bs[r][c] = (gk < K) ? B[(size_t)gk * N + col0 + c] : 0.f;
        }
        __syncthreads();
        #pragma unroll
        for (int kk = 0; kk < 32; ++kk) {
            float a[4], b[4];
            #pragma unroll
            for (int i = 0; i < 4; ++i) a[i] = As[ty * 4 + i][kk];
            #pragma unroll
            for (int j = 0; j < 4; ++j) b[j] = Bs[kk][tx * 4 + j];
            #pragma unroll
            for (int i = 0; i < 4; ++i)
                #pragma unroll
                for (int j = 0; j < 4; ++j)
                    acc[i][j] = fmaf(a[i], b[j], acc[i][j]);
        }
        __syncthreads();
    }

    #pragma unroll
    for (int i = 0; i < 4; ++i) {
        int r = row0 + ty * 4 + i;
        #pragma unroll
        for (int j = 0; j < 4; ++j) {
            int c = col0 + tx * 4 + j;
            float v = acc[i][j];
            if (bias) v += bias[c];
            if (EPI == 1) v = v / (1.f + expf(-v));                       // silu
            if (EPI == 2) v = 0.5f * v * (1.f + erff(v * 0.70710678f));    // gelu exact
            size_t idx = (size_t)r * N + c;
            if (ACC) v += C[idx];
            C[idx] = v;
        }
    }
}

// ---------------------------------------------------------------------------
// Row LayerNorm, one block per row. D = feature dim.
// ---------------------------------------------------------------------------
__global__ __launch_bounds__(256) void ln_f32(
    const float* __restrict__ x, const float* __restrict__ w,
    const float* __restrict__ b, float* __restrict__ y, int D)
{
    const int row = blockIdx.x;
    const float* xr = x + (size_t)row * D;
    float s = 0.f, ss = 0.f;
    for (int d = threadIdx.x; d < D; d += 256) {
        float v = xr[d];
        s += v; ss = fmaf(v, v, ss);
    }
    __shared__ float red[2][4];
    const int lane = threadIdx.x & 63, wid = threadIdx.x >> 6;
    #pragma unroll
    for (int off = 32; off; off >>= 1) {
        s  += __shfl_xor(s,  off);
        ss += __shfl_xor(ss, off);
    }
    if (lane == 0) { red[0][wid] = s; red[1][wid] = ss; }
    __syncthreads();
    s  = red[0][0] + red[0][1] + red[0][2] + red[0][3];
    ss = red[1][0] + red[1][1] + red[1][2] + red[1][3];
    const float mu  = s / D;
    const float var = ss / D - mu * mu;
    const float inv = rsqrtf(var + 1e-6f);
    float* yr = y + (size_t)row * D;
    for (int d = threadIdx.x; d < D; d += 256)
        yr[d] = (xr[d] - mu) * inv * w[d] + b[d];
}

// ---------------------------------------------------------------------------
// RoPE in place on qkv buffer (SEQ, 3, HEADS, HD). Applies to q and k.
// emb[s,d] = pos[s, (d%40)/20] * 10000^(-((d%40)%20)/20); rotate-half pairs (j, j+40).
// ---------------------------------------------------------------------------
__global__ __launch_bounds__(256) void rope_f32(
    float* __restrict__ qkv, const int* __restrict__ pos)
{
    int idx = blockIdx.x * 256 + threadIdx.x;
    const int total = SEQ * HEADS * 40;
    if (idx >= total) return;
    const int j = idx % 40;
    const int h = (idx / 40) % HEADS;
    const int s = idx / (40 * HEADS);
    const float p = (float)pos[s * 2 + (j / 20)];
    const float f = p * powf(10000.f, -(float)(j % 20) / 20.f);
    float c, sn;
    sincosf(f, &c, &sn);
    float* q = qkv + (size_t)s * QKVN + h * HD;
    float* k = q + EMBED;
    float q1 = q[j], q2 = q[j + 40];
    q[j]      = q1 * c - q2 * sn;
    q[j + 40] = q2 * c + q1 * sn;
    float k1 = k[j], k2 = k[j + 40];
    k[j]      = k1 * c - k2 * sn;
    k[j + 40] = k2 * c + k1 * sn;
}

// ---------------------------------------------------------------------------
// Flash-style attention within a segment. grid (HEADS, NSEG, SEGLEN/QPB).
// Block = 256 threads = 4 waves; each wave owns QPW=4 query rows.
// K/V staged in LDS chunks of 64 keys, stride 81 (odd -> 2-way aliasing = free).
// ---------------------------------------------------------------------------
#define QPB 16
#define QPW 4
#define KCH 64

__global__ __launch_bounds__(256) void attn_f32(
    const float* __restrict__ qkv, float* __restrict__ out)
{
    const int hh = blockIdx.x;
    const int seg = blockIdx.y;
    const int qbase = seg * SEGLEN + blockIdx.z * QPB;
    const int tid = threadIdx.x;
    const int lane = tid & 63, wid = tid >> 6;

    __shared__ float Ks[KCH][81];
    __shared__ float Vs[KCH][81];
    __shared__ float Qs[QPB][80];

    for (int t = tid; t < QPB * 80; t += 256) {
        int r = t / 80, d = t % 80;
        Qs[r][d] = qkv[(size_t)(qbase + r) * QKVN + hh * HD + d];
    }

    float m[QPW], l[QPW], oa[QPW], ob[QPW];
    #pragma unroll
    for (int i = 0; i < QPW; ++i) { m[i] = -1e30f; l[i] = 0.f; oa[i] = 0.f; ob[i] = 0.f; }

    const float scale = 0.11180339887498949f; // 1/sqrt(80)
    const int d2 = 64 + (lane & 15);

    for (int c0 = 0; c0 < SEGLEN; c0 += KCH) {
        __syncthreads();
        for (int t = tid; t < KCH * 80; t += 256) {
            int r = t / 80, d = t % 80;
            const float* base = qkv + (size_t)(seg * SEGLEN + c0 + r) * QKVN + hh * HD;
            Ks[r][d] = base[EMBED + d];       // k
            Vs[r][d] = base[2 * EMBED + d];   // v
        }
        __syncthreads();

        #pragma unroll
        for (int qi = 0; qi < QPW; ++qi) {
            const int qrow = wid * QPW + qi;
            float s = 0.f;
            #pragma unroll
            for (int d = 0; d < 80; ++d)
                s = fmaf(Qs[qrow][d], Ks[lane][d], s);
            s *= scale;
            float mx = s;
            #pragma unroll
            for (int off = 32; off; off >>= 1) mx = fmaxf(mx, __shfl_xor(mx, off));
            const float mn = fmaxf(m[qi], mx);
            const float corr = expf(m[qi] - mn);
            const float p = expf(s - mn);
            float ps = p;
            #pragma unroll
            for (int off = 32; off; off >>= 1) ps += __shfl_xor(ps, off);
            l[qi] = l[qi] * corr + ps;
            m[qi] = mn;
            oa[qi] *= corr; ob[qi] *= corr;
            for (int j = 0; j < KCH; ++j) {
                float pj = __shfl(p, j);
                oa[qi] = fmaf(pj, Vs[j][lane], oa[qi]);
                ob[qi] = fmaf(pj, Vs[j][d2], ob[qi]);
            }
        }
    }

    #pragma unroll
    for (int qi = 0; qi < QPW; ++qi) {
        const int qrow = qbase + wid * QPW + qi;
        const float inv = 1.f / l[qi];
        float* orow = out + (size_t)qrow * EMBED + hh * HD;
        orow[lane] = oa[qi] * inv;
        if (lane < 16) orow[d2] = ob[qi] * inv;
    }
}

// ---------------------------------------------------------------------------

extern "C" void kernel_launch(void* const* d_in, const int* in_sizes, int n_in,
                              void* d_out, int out_size, void* d_ws, size_t ws_size,
                              hipStream_t stream)
{
    const float* hs      = (const float*)d_in[0];
    const int*   pos     = (const int*)  d_in[1];
    // d_in[2] cu_seqlens: structure hardcoded (2 segments x 1024), inputs fixed
    const float* patch_w = (const float*)d_in[3];
    const float* ln1_w   = (const float*)d_in[4];
    const float* ln1_b   = (const float*)d_in[5];
    const float* ln2_w   = (const float*)d_in[6];
    const float* ln2_b   = (const float*)d_in[7];
    const float* qkv_w   = (const float*)d_in[8];
    const float* qkv_b   = (const float*)d_in[9];
    const float* proj_w  = (const float*)d_in[10];
    const float* proj_b  = (const float*)d_in[11];
    const float* fc1_w   = (const float*)d_in[12];
    const float* fc1_b   = (const float*)d_in[13];
    const float* fc2_w   = (const float*)d_in[14];
    const float* fc2_b   = (const float*)d_in[15];
    const float* mln_w   = (const float*)d_in[16];
    const float* mln_b   = (const float*)d_in[17];
    const float* w1      = (const float*)d_in[18];
    const float* b1      = (const float*)d_in[19];
    const float* w2      = (const float*)d_in[20];
    const float* b2      = (const float*)d_in[21];
    float* out = (float*)d_out;

    // workspace: x (SEQ*EMBED) | h (SEQ*EMBED) | big (SEQ*MLP)
    float* x   = (float*)d_ws;
    float* h   = x + (size_t)SEQ * EMBED;
    float* big = h + (size_t)SEQ * EMBED;
    // attention output aliases h (free after qkv GEMM)

    const dim3 gblk(16, 16);
    auto ggrid = [](int M, int N) { return dim3(N / 64, M / 64); };

    // patch embed: x = hs @ patch_w
    gemm_f32<0, 0><<<ggrid(SEQ, EMBED), gblk, 0, stream>>>(
        hs, patch_w, nullptr, x, SEQ, EMBED, PATCH_IN);

    for (int i = 0; i < 2; ++i) {
        ln_f32<<<SEQ, 256, 0, stream>>>(x, ln1_w + i * EMBED, ln1_b + i * EMBED, h, EMBED);
        gemm_f32<0, 0><<<ggrid(SEQ, QKVN), gblk, 0, stream>>>(
            h, qkv_w + (size_t)i * EMBED * QKVN, qkv_b + i * QKVN, big, SEQ, QKVN, EMBED);
        rope_f32<<<(SEQ * HEADS * 40 + 255) / 256, 256, 0, stream>>>(big, pos);
        attn_f32<<<dim3(HEADS, NSEG, SEGLEN / QPB), 256, 0, stream>>>(big, h);
        gemm_f32<0, 1><<<ggrid(SEQ, EMBED), gblk, 0, stream>>>(
            h, proj_w + (size_t)i * EMBED * EMBED, proj_b + i * EMBED, x, SEQ, EMBED, EMBED);
        ln_f32<<<SEQ, 256, 0, stream>>>(x, ln2_w + i * EMBED, ln2_b + i * EMBED, h, EMBED);
        gemm_f32<1, 0><<<ggrid(SEQ, MLP), gblk, 0, stream>>>(
            h, fc1_w + (size_t)i * EMBED * MLP, fc1_b + i * MLP, big, SEQ, MLP, EMBED);
        gemm_f32<0, 1><<<ggrid(SEQ, EMBED), gblk, 0, stream>>>(
            big, fc2_w + (size_t)i * MLP * EMBED, fc2_b + i * EMBED, x, SEQ, EMBED, MLP);
    }

    // merger: h = LN(x) viewed as (512, 5120); big = gelu(h@w1+b1); out = big@w2+b2
    ln_f32<<<SEQ, 256, 0, stream>>>(x, mln_w, mln_b, h, EMBED);
    gemm_f32<2, 0><<<ggrid(MROWS, HIDDEN), gblk, 0, stream>>>(
        h, w1, b1, big, MROWS, HIDDEN, 4 * EMBED);
    gemm_f32<0, 0><<<ggrid(MROWS, HIDDEN), gblk, 0, stream>>>(
        big, w2, b2, out, MROWS, HIDDEN, HIDDEN);
}

// Round 2
// 2403.588 us; speedup vs baseline: 4.6650x; 4.6650x over previous
//
#include <hip/hip_runtime.h>
#include <math.h>

#define SEQ    2048
#define EMBED  1280
#define HEADS  16
#define HD     80
#define MLP    5120
#define HIDDEN 3584
#define QKVN   3840
#define SEGLEN 1024
#define NSEG   2
#define PATCH_IN 1176
#define PATCH_KP 1184   // padded to mult of 32
#define MROWS  512

typedef __attribute__((ext_vector_type(8))) short bf16x8;
typedef __attribute__((ext_vector_type(4))) float f32x4;
typedef unsigned short ushort_t;

__device__ __forceinline__ ushort_t f2bf(float f) {
    unsigned u = __builtin_bit_cast(unsigned, f);
    unsigned r = u + 0x7FFFu + ((u >> 16) & 1u);   // RNE
    return (ushort_t)(r >> 16);
}

__device__ __forceinline__ void gld_lds16(const void* g, void* l) {
    __builtin_amdgcn_global_load_lds(
        (const __attribute__((address_space(1))) void*)g,
        (__attribute__((address_space(3))) void*)l, 16, 0, 0);
}

// ---------------------------------------------------------------------------
// bf16 MFMA GEMM: C = epi(A@B^T' + bias) (+C if ACC).
// A: (M,K) bf16 row-major.  Bt: (N,K) bf16 row-major (i.e. B transposed).
// M,N mult of 128; K mult of 32. EPI: 0 none, 1 silu, 2 gelu. OBF: out bf16.
// 128x128 tile, BK=32, 256 thr = 4 waves, each wave 64x64 via 4x4 16x16 frags.
// ---------------------------------------------------------------------------
template<int EPI, int ACC, int OBF>
__global__ __launch_bounds__(256) void gemm_bf16(
    const ushort_t* __restrict__ A, const ushort_t* __restrict__ Bt,
    const float* __restrict__ bias, void* __restrict__ Cout,
    int M, int N, int K)
{
    __shared__ short Abuf[128 * 32];
    __shared__ short Bbuf[128 * 32];

    const int tid  = threadIdx.x;
    const int lane = tid & 63, wid = tid >> 6;
    const int wr = wid >> 1, wc = wid & 1;
    const int row0 = blockIdx.y * 128, col0 = blockIdx.x * 128;

    // staging decomposition: seg = tid + i*256; r = seg>>2 (row), ks = seg&3 (16B slot)
    const int r0 = tid >> 2, ks0 = tid & 3;

    f32x4 acc[4][4] = {};

    const int lrow = lane & 15;
    const int koff = (lane >> 4) * 8;   // element offset in k within LDS row

    for (int k0 = 0; k0 < K; k0 += 32) {
        __syncthreads();
        {
            const ushort_t* ga0 = A  + (size_t)(row0 + r0) * K + k0 + ks0 * 8;
            const ushort_t* ga1 = A  + (size_t)(row0 + r0 + 64) * K + k0 + ks0 * 8;
            const ushort_t* gb0 = Bt + (size_t)(col0 + r0) * K + k0 + ks0 * 8;
            const ushort_t* gb1 = Bt + (size_t)(col0 + r0 + 64) * K + k0 + ks0 * 8;
            gld_lds16(ga0, &Abuf[(size_t)tid * 8]);
            gld_lds16(ga1, &Abuf[(size_t)(tid + 256) * 8]);
            gld_lds16(gb0, &Bbuf[(size_t)tid * 8]);
            gld_lds16(gb1, &Bbuf[(size_t)(tid + 256) * 8]);
        }
        __syncthreads();

        bf16x8 a[4], b[4];
        #pragma unroll
        for (int m = 0; m < 4; ++m)
            a[m] = *(const bf16x8*)&Abuf[(wr * 64 + m * 16 + lrow) * 32 + koff];
        #pragma unroll
        for (int n = 0; n < 4; ++n)
            b[n] = *(const bf16x8*)&Bbuf[(wc * 64 + n * 16 + lrow) * 32 + koff];
        #pragma unroll
        for (int m = 0; m < 4; ++m)
            #pragma unroll
            for (int n = 0; n < 4; ++n)
                acc[m][n] = __builtin_amdgcn_mfma_f32_16x16x32_bf16(
                    a[m], b[n], acc[m][n], 0, 0, 0);
    }

    // epilogue: C/D layout col = lane&15, row = (lane>>4)*4 + reg
    const int rbase = (lane >> 4) * 4;
    #pragma unroll
    for (int n = 0; n < 4; ++n) {
        const int c = col0 + wc * 64 + n * 16 + lrow;
        const float bv = bias ? bias[c] : 0.f;
        #pragma unroll
        for (int m = 0; m < 4; ++m) {
            const int rb = row0 + wr * 64 + m * 16 + rbase;
            #pragma unroll
            for (int g = 0; g < 4; ++g) {
                float v = acc[m][n][g] + bv;
                if (EPI == 1) v = v / (1.f + expf(-v));
                if (EPI == 2) v = 0.5f * v * (1.f + erff(v * 0.70710678f));
                const size_t idx = (size_t)(rb + g) * N + c;
                if (OBF) {
                    ((ushort_t*)Cout)[idx] = f2bf(v);
                } else {
                    float* Cf = (float*)Cout;
                    if (ACC) v += Cf[idx];
                    Cf[idx] = v;
                }
            }
        }
    }
}

// ---------------------------------------------------------------------------
// transpose + f32->bf16 cast: in (K,N) f32 -> out (N,Kp) bf16, zero-pad k>=K.
// grid (N/32, Kp/32), block (32,8).
// ---------------------------------------------------------------------------
__global__ __launch_bounds__(256) void transpose_cast(
    const float* __restrict__ in, ushort_t* __restrict__ out, int K, int N, int Kp)
{
    __shared__ float t[32][33];
    const int n0 = blockIdx.x * 32, k0 = blockIdx.y * 32;
    const int tx = threadIdx.x, ty = threadIdx.y;
    #pragma unroll
    for (int j = 0; j < 4; ++j) {
        int k = k0 + ty + j * 8;
        t[ty + j * 8][tx] = (k < K) ? in[(size_t)k * N + n0 + tx] : 0.f;
    }
    __syncthreads();
    #pragma unroll
    for (int j = 0; j < 4; ++j) {
        int n = n0 + ty + j * 8;
        out[(size_t)n * Kp + k0 + tx] = f2bf(t[tx][ty + j * 8]);
    }
}

// cast hs (SEQ, PATCH_IN) f32 -> (SEQ, PATCH_KP) bf16 zero-padded
__global__ __launch_bounds__(256) void cast_hs(
    const float* __restrict__ in, ushort_t* __restrict__ out)
{
    int idx = blockIdx.x * 256 + threadIdx.x;
    if (idx >= SEQ * PATCH_KP) return;
    int s = idx / PATCH_KP, k = idx % PATCH_KP;
    out[idx] = (k < PATCH_IN) ? f2bf(in[(size_t)s * PATCH_IN + k]) : 0;
}

// ---------------------------------------------------------------------------
// Row LayerNorm f32 in -> bf16 out
// ---------------------------------------------------------------------------
__global__ __launch_bounds__(256) void ln_f32(
    const float* __restrict__ x, const float* __restrict__ w,
    const float* __restrict__ b, ushort_t* __restrict__ y, int D)
{
    const int row = blockIdx.x;
    const float* xr = x + (size_t)row * D;
    float s = 0.f, ss = 0.f;
    for (int d = threadIdx.x; d < D; d += 256) {
        float v = xr[d];
        s += v; ss = fmaf(v, v, ss);
    }
    __shared__ float red[2][4];
    const int lane = threadIdx.x & 63, wid = threadIdx.x >> 6;
    #pragma unroll
    for (int off = 32; off; off >>= 1) {
        s  += __shfl_xor(s,  off);
        ss += __shfl_xor(ss, off);
    }
    if (lane == 0) { red[0][wid] = s; red[1][wid] = ss; }
    __syncthreads();
    s  = red[0][0] + red[0][1] + red[0][2] + red[0][3];
    ss = red[1][0] + red[1][1] + red[1][2] + red[1][3];
    const float mu  = s / D;
    const float var = ss / D - mu * mu;
    const float inv = rsqrtf(var + 1e-6f);
    ushort_t* yr = y + (size_t)row * D;
    for (int d = threadIdx.x; d < D; d += 256)
        yr[d] = f2bf((xr[d] - mu) * inv * w[d] + b[d]);
}

// ---------------------------------------------------------------------------
// RoPE in place on qkv f32 buffer (SEQ, 3, HEADS, HD); applies to q and k.
// ---------------------------------------------------------------------------
__global__ __launch_bounds__(256) void rope_f32(
    float* __restrict__ qkv, const int* __restrict__ pos)
{
    int idx = blockIdx.x * 256 + threadIdx.x;
    const int total = SEQ * HEADS * 40;
    if (idx >= total) return;
    const int j = idx % 40;
    const int h = (idx / 40) % HEADS;
    const int s = idx / (40 * HEADS);
    const float p = (float)pos[s * 2 + (j / 20)];
    const float f = p * powf(10000.f, -(float)(j % 20) / 20.f);
    float c, sn;
    sincosf(f, &c, &sn);
    float* q = qkv + (size_t)s * QKVN + h * HD;
    float* k = q + EMBED;
    float q1 = q[j], q2 = q[j + 40];
    q[j]      = q1 * c - q2 * sn;
    q[j + 40] = q2 * c + q1 * sn;
    float k1 = k[j], k2 = k[j + 40];
    k[j]      = k1 * c - k2 * sn;
    k[j + 40] = k2 * c + k1 * sn;
}

// ---------------------------------------------------------------------------
// Flash attention per segment, f32, out bf16. grid (HEADS, NSEG, SEGLEN/16).
// ---------------------------------------------------------------------------
#define QPB 16
#define QPW 4
#define KCH 64

__global__ __launch_bounds__(256) void attn_f32(
    const float* __restrict__ qkv, ushort_t* __restrict__ out)
{
    const int hh = blockIdx.x;
    const int seg = blockIdx.y;
    const int qbase = seg * SEGLEN + blockIdx.z * QPB;
    const int tid = threadIdx.x;
    const int lane = tid & 63, wid = tid >> 6;

    __shared__ float Ks[KCH][81];
    __shared__ float Vs[KCH][81];
    __shared__ float Qs[QPB][80];

    for (int t = tid; t < QPB * 80; t += 256) {
        int r = t / 80, d = t % 80;
        Qs[r][d] = qkv[(size_t)(qbase + r) * QKVN + hh * HD + d];
    }

    float m[QPW], l[QPW], oa[QPW], ob[QPW];
    #pragma unroll
    for (int i = 0; i < QPW; ++i) { m[i] = -1e30f; l[i] = 0.f; oa[i] = 0.f; ob[i] = 0.f; }

    const float scale = 0.11180339887498949f;
    const int d2 = 64 + (lane & 15);

    for (int c0 = 0; c0 < SEGLEN; c0 += KCH) {
        __syncthreads();
        for (int t = tid; t < KCH * 80; t += 256) {
            int r = t / 80, d = t % 80;
            const float* base = qkv + (size_t)(seg * SEGLEN + c0 + r) * QKVN + hh * HD;
            Ks[r][d] = base[EMBED + d];
            Vs[r][d] = base[2 * EMBED + d];
        }
        __syncthreads();

        #pragma unroll
        for (int qi = 0; qi < QPW; ++qi) {
            const int qrow = wid * QPW + qi;
            float s = 0.f;
            #pragma unroll
            for (int d = 0; d < 80; ++d)
                s = fmaf(Qs[qrow][d], Ks[lane][d], s);
            s *= scale;
            float mx = s;
            #pragma unroll
            for (int off = 32; off; off >>= 1) mx = fmaxf(mx, __shfl_xor(mx, off));
            const float mn = fmaxf(m[qi], mx);
            const float corr = expf(m[qi] - mn);
            const float p = expf(s - mn);
            float ps = p;
            #pragma unroll
            for (int off = 32; off; off >>= 1) ps += __shfl_xor(ps, off);
            l[qi] = l[qi] * corr + ps;
            m[qi] = mn;
            oa[qi] *= corr; ob[qi] *= corr;
            for (int j = 0; j < KCH; ++j) {
                float pj = __shfl(p, j);
                oa[qi] = fmaf(pj, Vs[j][lane], oa[qi]);
                ob[qi] = fmaf(pj, Vs[j][d2], ob[qi]);
            }
        }
    }

    #pragma unroll
    for (int qi = 0; qi < QPW; ++qi) {
        const int qrow = qbase + wid * QPW + qi;
        const float inv = 1.f / l[qi];
        ushort_t* orow = out + (size_t)qrow * EMBED + hh * HD;
        orow[lane] = f2bf(oa[qi] * inv);
        if (lane < 16) orow[d2] = f2bf(ob[qi] * inv);
    }
}

// ---------------------------------------------------------------------------

extern "C" void kernel_launch(void* const* d_in, const int* in_sizes, int n_in,
                              void* d_out, int out_size, void* d_ws, size_t ws_size,
                              hipStream_t stream)
{
    const float* hs      = (const float*)d_in[0];
    const int*   pos     = (const int*)  d_in[1];
    const float* patch_w = (const float*)d_in[3];
    const float* ln1_w   = (const float*)d_in[4];
    const float* ln1_b   = (const float*)d_in[5];
    const float* ln2_w   = (const float*)d_in[6];
    const float* ln2_b   = (const float*)d_in[7];
    const float* qkv_w   = (const float*)d_in[8];
    const float* qkv_b   = (const float*)d_in[9];
    const float* proj_w  = (const float*)d_in[10];
    const float* proj_b  = (const float*)d_in[11];
    const float* fc1_w   = (const float*)d_in[12];
    const float* fc1_b   = (const float*)d_in[13];
    const float* fc2_w   = (const float*)d_in[14];
    const float* fc2_b   = (const float*)d_in[15];
    const float* mln_w   = (const float*)d_in[16];
    const float* mln_b   = (const float*)d_in[17];
    const float* w1      = (const float*)d_in[18];
    const float* b1      = (const float*)d_in[19];
    const float* w2      = (const float*)d_in[20];
    const float* b2      = (const float*)d_in[21];
    float* out = (float*)d_out;

    // ws carve (bytes):
    // x      f32 2048x1280   = 10.50 MB
    // qkvbuf f32 2048x3840   = 31.46 MB  (also reused as bf16 fc1out / mrg1out)
    // hbf    bf16 2048x1280  =  5.24 MB
    // hsbf   bf16 2048x1184  =  4.85 MB
    // wbuf   bf16 3584x5120  = 36.70 MB  (per-GEMM transposed weight)
    char* p = (char*)d_ws;
    float*    x      = (float*)p;            p += (size_t)SEQ * EMBED * 4;
    float*    qkvbuf = (float*)p;            p += (size_t)SEQ * QKVN * 4;
    ushort_t* hbf    = (ushort_t*)p;         p += (size_t)SEQ * EMBED * 2;
    ushort_t* hsbf   = (ushort_t*)p;         p += (size_t)SEQ * PATCH_KP * 2;
    ushort_t* wbuf   = (ushort_t*)p;
    ushort_t* fc1out = (ushort_t*)qkvbuf;    // alias: qkv consumed before fc1

    const dim3 tblk(32, 8);
    auto tgrid = [](int N, int Kp) { return dim3(N / 32, Kp / 32); };
    auto ggrid = [](int M, int N) { return dim3(N / 128, M / 128); };

    // patch embed: x = hs @ patch_w
    cast_hs<<<(SEQ * PATCH_KP + 255) / 256, 256, 0, stream>>>(hs, hsbf);
    transpose_cast<<<tgrid(EMBED, PATCH_KP), tblk, 0, stream>>>(
        patch_w, wbuf, PATCH_IN, EMBED, PATCH_KP);
    gemm_bf16<0, 0, 0><<<ggrid(SEQ, EMBED), 256, 0, stream>>>(
        hsbf, wbuf, nullptr, x, SEQ, EMBED, PATCH_KP);

    for (int i = 0; i < 2; ++i) {
        ln_f32<<<SEQ, 256, 0, stream>>>(x, ln1_w + i * EMBED, ln1_b + i * EMBED, hbf, EMBED);
        transpose_cast<<<tgrid(QKVN, EMBED), tblk, 0, stream>>>(
            qkv_w + (size_t)i * EMBED * QKVN, wbuf, EMBED, QKVN, EMBED);
        gemm_bf16<0, 0, 0><<<ggrid(SEQ, QKVN), 256, 0, stream>>>(
            hbf, wbuf, qkv_b + i * QKVN, qkvbuf, SEQ, QKVN, EMBED);
        rope_f32<<<(SEQ * HEADS * 40 + 255) / 256, 256, 0, stream>>>(qkvbuf, pos);
        attn_f32<<<dim3(HEADS, NSEG, SEGLEN / QPB), 256, 0, stream>>>(qkvbuf, hbf);
        transpose_cast<<<tgrid(EMBED, EMBED), tblk, 0, stream>>>(
            proj_w + (size_t)i * EMBED * EMBED, wbuf, EMBED, EMBED, EMBED);
        gemm_bf16<0, 1, 0><<<ggrid(SEQ, EMBED), 256, 0, stream>>>(
            hbf, wbuf, proj_b + i * EMBED, x, SEQ, EMBED, EMBED);
        ln_f32<<<SEQ, 256, 0, stream>>>(x, ln2_w + i * EMBED, ln2_b + i * EMBED, hbf, EMBED);
        transpose_cast<<<tgrid(MLP, EMBED), tblk, 0, stream>>>(
            fc1_w + (size_t)i * EMBED * MLP, wbuf, EMBED, MLP, EMBED);
        gemm_bf16<1, 0, 1><<<ggrid(SEQ, MLP), 256, 0, stream>>>(
            hbf, wbuf, fc1_b + i * MLP, fc1out, SEQ, MLP, EMBED);
        transpose_cast<<<tgrid(EMBED, MLP), tblk, 0, stream>>>(
            fc2_w + (size_t)i * MLP * EMBED, wbuf, MLP, EMBED, MLP);
        gemm_bf16<0, 1, 0><<<ggrid(SEQ, EMBED), 256, 0, stream>>>(
            fc1out, wbuf, fc2_b + i * EMBED, x, SEQ, EMBED, MLP);
    }

    // merger
    ln_f32<<<SEQ, 256, 0, stream>>>(x, mln_w, mln_b, hbf, EMBED);
    transpose_cast<<<tgrid(HIDDEN, 4 * EMBED), tblk, 0, stream>>>(
        w1, wbuf, 4 * EMBED, HIDDEN, 4 * EMBED);
    gemm_bf16<2, 0, 1><<<ggrid(MROWS, HIDDEN), 256, 0, stream>>>(
        hbf, wbuf, b1, fc1out, MROWS, HIDDEN, 4 * EMBED);
    transpose_cast<<<tgrid(HIDDEN, HIDDEN), tblk, 0, stream>>>(
        w2, wbuf, HIDDEN, HIDDEN, HIDDEN);
    gemm_bf16<0, 0, 0><<<ggrid(MROWS, HIDDEN), 256, 0, stream>>>(
        fc1out, wbuf, b2, out, MROWS, HIDDEN, HIDDEN);
}

// Round 3
// 1094.743 us; speedup vs baseline: 10.2424x; 2.1956x over previous
//
#include <hip/hip_runtime.h>
#include <math.h>

#define SEQ    2048
#define EMBED  1280
#define HEADS  16
#define HD     80
#define MLP    5120
#define HIDDEN 3584
#define QKVN   3840
#define SEGLEN 1024
#define NSEG   2
#define PATCH_IN 1176
#define PATCH_KP 1184
#define MROWS  512

typedef __attribute__((ext_vector_type(8))) short bf16x8;
typedef __attribute__((ext_vector_type(4))) float f32x4;
typedef unsigned short ushort_t;

__device__ __forceinline__ ushort_t f2bf(float f) {
    unsigned u = __builtin_bit_cast(unsigned, f);
    unsigned r = u + 0x7FFFu + ((u >> 16) & 1u);   // RNE
    return (ushort_t)(r >> 16);
}

__device__ __forceinline__ void gld_lds16(const void* g, void* l) {
    __builtin_amdgcn_global_load_lds(
        (const __attribute__((address_space(1))) void*)g,
        (__attribute__((address_space(3))) void*)l, 16, 0, 0);
}

// ---------------------------------------------------------------------------
// bf16 MFMA GEMM (unchanged from round 2): C = epi(A@Bt + bias) (+C if ACC).
// ---------------------------------------------------------------------------
template<int EPI, int ACC, int OBF>
__global__ __launch_bounds__(256) void gemm_bf16(
    const ushort_t* __restrict__ A, const ushort_t* __restrict__ Bt,
    const float* __restrict__ bias, void* __restrict__ Cout,
    int M, int N, int K)
{
    __shared__ __align__(16) short Abuf[128 * 32];
    __shared__ __align__(16) short Bbuf[128 * 32];

    const int tid  = threadIdx.x;
    const int lane = tid & 63, wid = tid >> 6;
    const int wr = wid >> 1, wc = wid & 1;
    const int row0 = blockIdx.y * 128, col0 = blockIdx.x * 128;
    const int r0 = tid >> 2, ks0 = tid & 3;

    f32x4 acc[4][4] = {};

    const int lrow = lane & 15;
    const int koff = (lane >> 4) * 8;

    for (int k0 = 0; k0 < K; k0 += 32) {
        __syncthreads();
        {
            const ushort_t* ga0 = A  + (size_t)(row0 + r0) * K + k0 + ks0 * 8;
            const ushort_t* ga1 = A  + (size_t)(row0 + r0 + 64) * K + k0 + ks0 * 8;
            const ushort_t* gb0 = Bt + (size_t)(col0 + r0) * K + k0 + ks0 * 8;
            const ushort_t* gb1 = Bt + (size_t)(col0 + r0 + 64) * K + k0 + ks0 * 8;
            gld_lds16(ga0, &Abuf[(size_t)tid * 8]);
            gld_lds16(ga1, &Abuf[(size_t)(tid + 256) * 8]);
            gld_lds16(gb0, &Bbuf[(size_t)tid * 8]);
            gld_lds16(gb1, &Bbuf[(size_t)(tid + 256) * 8]);
        }
        __syncthreads();

        bf16x8 a[4], b[4];
        #pragma unroll
        for (int m = 0; m < 4; ++m)
            a[m] = *(const bf16x8*)&Abuf[(wr * 64 + m * 16 + lrow) * 32 + koff];
        #pragma unroll
        for (int n = 0; n < 4; ++n)
            b[n] = *(const bf16x8*)&Bbuf[(wc * 64 + n * 16 + lrow) * 32 + koff];
        #pragma unroll
        for (int m = 0; m < 4; ++m)
            #pragma unroll
            for (int n = 0; n < 4; ++n)
                acc[m][n] = __builtin_amdgcn_mfma_f32_16x16x32_bf16(
                    a[m], b[n], acc[m][n], 0, 0, 0);
    }

    const int rbase = (lane >> 4) * 4;
    #pragma unroll
    for (int n = 0; n < 4; ++n) {
        const int c = col0 + wc * 64 + n * 16 + lrow;
        const float bv = bias ? bias[c] : 0.f;
        #pragma unroll
        for (int m = 0; m < 4; ++m) {
            const int rb = row0 + wr * 64 + m * 16 + rbase;
            #pragma unroll
            for (int g = 0; g < 4; ++g) {
                float v = acc[m][n][g] + bv;
                if (EPI == 1) v = v / (1.f + expf(-v));
                if (EPI == 2) v = 0.5f * v * (1.f + erff(v * 0.70710678f));
                const size_t idx = (size_t)(rb + g) * N + c;
                if (OBF) {
                    ((ushort_t*)Cout)[idx] = f2bf(v);
                } else {
                    float* Cf = (float*)Cout;
                    if (ACC) v += Cf[idx];
                    Cf[idx] = v;
                }
            }
        }
    }
}

// ---------------------------------------------------------------------------
// transpose + cast (unchanged)
// ---------------------------------------------------------------------------
__global__ __launch_bounds__(256) void transpose_cast(
    const float* __restrict__ in, ushort_t* __restrict__ out, int K, int N, int Kp)
{
    __shared__ float t[32][33];
    const int n0 = blockIdx.x * 32, k0 = blockIdx.y * 32;
    const int tx = threadIdx.x, ty = threadIdx.y;
    #pragma unroll
    for (int j = 0; j < 4; ++j) {
        int k = k0 + ty + j * 8;
        t[ty + j * 8][tx] = (k < K) ? in[(size_t)k * N + n0 + tx] : 0.f;
    }
    __syncthreads();
    #pragma unroll
    for (int j = 0; j < 4; ++j) {
        int n = n0 + ty + j * 8;
        out[(size_t)n * Kp + k0 + tx] = f2bf(t[tx][ty + j * 8]);
    }
}

__global__ __launch_bounds__(256) void cast_hs(
    const float* __restrict__ in, ushort_t* __restrict__ out)
{
    int idx = blockIdx.x * 256 + threadIdx.x;
    if (idx >= SEQ * PATCH_KP) return;
    int s = idx / PATCH_KP, k = idx % PATCH_KP;
    out[idx] = (k < PATCH_IN) ? f2bf(in[(size_t)s * PATCH_IN + k]) : 0;
}

// ---------------------------------------------------------------------------
// LayerNorm (unchanged)
// ---------------------------------------------------------------------------
__global__ __launch_bounds__(256) void ln_f32(
    const float* __restrict__ x, const float* __restrict__ w,
    const float* __restrict__ b, ushort_t* __restrict__ y, int D)
{
    const int row = blockIdx.x;
    const float* xr = x + (size_t)row * D;
    float s = 0.f, ss = 0.f;
    for (int d = threadIdx.x; d < D; d += 256) {
        float v = xr[d];
        s += v; ss = fmaf(v, v, ss);
    }
    __shared__ float red[2][4];
    const int lane = threadIdx.x & 63, wid = threadIdx.x >> 6;
    #pragma unroll
    for (int off = 32; off; off >>= 1) {
        s  += __shfl_xor(s,  off);
        ss += __shfl_xor(ss, off);
    }
    if (lane == 0) { red[0][wid] = s; red[1][wid] = ss; }
    __syncthreads();
    s  = red[0][0] + red[0][1] + red[0][2] + red[0][3];
    ss = red[1][0] + red[1][1] + red[1][2] + red[1][3];
    const float mu  = s / D;
    const float var = ss / D - mu * mu;
    const float inv = rsqrtf(var + 1e-6f);
    ushort_t* yr = y + (size_t)row * D;
    for (int d = threadIdx.x; d < D; d += 256)
        yr[d] = f2bf((xr[d] - mu) * inv * w[d] + b[d]);
}

// ---------------------------------------------------------------------------
// RoPE + scale + bf16 cast + head-major relayout for q,k.
// qb/kb: [H][SEQ][96], elements 80..95 zeroed. q pre-scaled by 1/sqrt(80).
// ---------------------------------------------------------------------------
__global__ __launch_bounds__(256) void rope_cast_qk(
    const float* __restrict__ qkv, const int* __restrict__ pos,
    ushort_t* __restrict__ qb, ushort_t* __restrict__ kb)
{
    int idx = blockIdx.x * 256 + threadIdx.x;   // (s, h, j), j < 48
    const int j = idx % 48;
    const int h = (idx / 48) % HEADS;
    const int s = idx / (48 * HEADS);
    if (s >= SEQ) return;
    const size_t ob = ((size_t)h * SEQ + s) * 96;
    if (j >= 40) {   // zero pad elements 80..95
        qb[ob + 40 + j] = 0; qb[ob + 48 + j] = 0;
        kb[ob + 40 + j] = 0; kb[ob + 48 + j] = 0;
        return;
    }
    const float p = (float)pos[s * 2 + (j / 20)];
    const float f = p * powf(10000.f, -(float)(j % 20) / 20.f);
    float c, sn;
    sincosf(f, &c, &sn);
    const float* q = qkv + (size_t)s * QKVN + h * HD;
    const float* k = q + EMBED;
    const float scale = 0.11180339887498949f;   // 1/sqrt(80), folded into q
    float q1 = q[j], q2 = q[j + 40];
    qb[ob + j]      = f2bf((q1 * c - q2 * sn) * scale);
    qb[ob + j + 40] = f2bf((q2 * c + q1 * sn) * scale);
    float k1 = k[j], k2 = k[j + 40];
    kb[ob + j]      = f2bf(k1 * c - k2 * sn);
    kb[ob + j + 40] = f2bf(k2 * c + k1 * sn);
}

// v transpose: vtb[h][d][s] = bf16(qkv[s][2E + h*80 + d])
__global__ __launch_bounds__(256) void v_transpose(
    const float* __restrict__ qkv, ushort_t* __restrict__ vtb)
{
    int idx = blockIdx.x * 256 + threadIdx.x;   // (h, d, s), s fastest
    int s = idx & (SEQ - 1);
    int d = (idx >> 11) % 80;
    int h = idx / (SEQ * 80);
    if (h >= HEADS) return;
    vtb[((size_t)h * 80 + d) * SEQ + s] =
        f2bf(qkv[(size_t)s * QKVN + 2 * EMBED + h * HD + d]);
}

// ---------------------------------------------------------------------------
// MFMA flash attention. grid (HEADS, NSEG, SEGLEN/64). 4 waves x 16 q rows.
// ---------------------------------------------------------------------------
#define AKC  64
#define KSTR 104
#define VSTR 72
#define PSTR 72

__global__ __launch_bounds__(256) void attn_mfma(
    const ushort_t* __restrict__ qb, const ushort_t* __restrict__ kb,
    const ushort_t* __restrict__ vtb, ushort_t* __restrict__ out)
{
    const int hh = blockIdx.x;
    const int seg = blockIdx.y;
    const int tid = threadIdx.x, lane = tid & 63, wid = tid >> 6;
    const int lr = lane & 15, lg = lane >> 4;

    __shared__ __align__(16) short Ks[AKC * KSTR];
    __shared__ __align__(16) short Vs[80 * VSTR];
    __shared__ __align__(16) short Ps[4][16 * PSTR];

    const int sq = seg * SEGLEN;
    const int qrow0 = sq + blockIdx.z * 64 + wid * 16;

    // Q fragments (A-layout: row=lr, k=f*32+lg*8)
    bf16x8 qf[3];
    #pragma unroll
    for (int f = 0; f < 3; ++f)
        qf[f] = *(const bf16x8*)&qb[((size_t)hh * SEQ + qrow0 + lr) * 96 + f * 32 + lg * 8];

    f32x4 o[5] = {};
    float m[4], l[4];
    #pragma unroll
    for (int g = 0; g < 4; ++g) { m[g] = -1e30f; l[g] = 0.f; }

    for (int c0 = 0; c0 < SEGLEN; c0 += AKC) {
        __syncthreads();
        #pragma unroll
        for (int i = 0; i < 3; ++i) {           // K: 64 rows x 12 slots
            int id = tid + i * 256;
            int r = id / 12, s = id % 12;
            *(bf16x8*)&Ks[r * KSTR + s * 8] =
                *(const bf16x8*)&kb[((size_t)hh * SEQ + sq + c0 + r) * 96 + s * 8];
        }
        #pragma unroll
        for (int i = 0; i < 3; ++i) {           // Vt: 80 rows x 8 slots
            int id = tid + i * 256;
            if (id < 640) {
                int d = id / 8, s = id % 8;
                *(bf16x8*)&Vs[d * VSTR + s * 8] =
                    *(const bf16x8*)&vtb[((size_t)hh * 80 + d) * SEQ + sq + c0 + s * 8];
            }
        }
        __syncthreads();

        // QK^T: D col=key, row=q
        f32x4 sc[4] = {};
        #pragma unroll
        for (int kt = 0; kt < 4; ++kt)
            #pragma unroll
            for (int f = 0; f < 3; ++f) {
                bf16x8 kf = *(const bf16x8*)&Ks[(kt * 16 + lr) * KSTR + f * 32 + lg * 8];
                sc[kt] = __builtin_amdgcn_mfma_f32_16x16x32_bf16(qf[f], kf, sc[kt], 0, 0, 0);
            }

        // online softmax (keys live across lanes 1,2,4,8 of the 16-group)
        float corr[4], ps[4];
        #pragma unroll
        for (int g = 0; g < 4; ++g) {
            float v = fmaxf(fmaxf(sc[0][g], sc[1][g]), fmaxf(sc[2][g], sc[3][g]));
            v = fmaxf(v, __shfl_xor(v, 1));
            v = fmaxf(v, __shfl_xor(v, 2));
            v = fmaxf(v, __shfl_xor(v, 4));
            v = fmaxf(v, __shfl_xor(v, 8));
            const float mn = fmaxf(m[g], v);
            corr[g] = __expf(m[g] - mn);
            m[g] = mn;
            ps[g] = 0.f;
        }
        #pragma unroll
        for (int kt = 0; kt < 4; ++kt)
            #pragma unroll
            for (int g = 0; g < 4; ++g) {
                float p = __expf(sc[kt][g] - m[g]);
                ps[g] += p;
                Ps[wid][(lg * 4 + g) * PSTR + kt * 16 + lr] = f2bf(p);
            }
        #pragma unroll
        for (int g = 0; g < 4; ++g) {
            float rs = ps[g];
            rs += __shfl_xor(rs, 1);
            rs += __shfl_xor(rs, 2);
            rs += __shfl_xor(rs, 4);
            rs += __shfl_xor(rs, 8);
            l[g] = l[g] * corr[g] + rs;
        }
        #pragma unroll
        for (int n = 0; n < 5; ++n)
            #pragma unroll
            for (int g = 0; g < 4; ++g) o[n][g] *= corr[g];

        // PV: A=P (per-wave LDS, same-wave ordering -> no barrier), B=Vt
        #pragma unroll
        for (int jf = 0; jf < 2; ++jf) {
            bf16x8 pa = *(const bf16x8*)&Ps[wid][lr * PSTR + jf * 32 + lg * 8];
            #pragma unroll
            for (int n = 0; n < 5; ++n) {
                bf16x8 vf = *(const bf16x8*)&Vs[(n * 16 + lr) * VSTR + jf * 32 + lg * 8];
                o[n] = __builtin_amdgcn_mfma_f32_16x16x32_bf16(pa, vf, o[n], 0, 0, 0);
            }
        }
    }

    #pragma unroll
    for (int g = 0; g < 4; ++g) {
        const float inv = 1.f / l[g];
        const int r = qrow0 + lg * 4 + g;
        #pragma unroll
        for (int n = 0; n < 5; ++n)
            out[(size_t)r * EMBED + hh * HD + n * 16 + lr] = f2bf(o[n][g] * inv);
    }
}

// ---------------------------------------------------------------------------

extern "C" void kernel_launch(void* const* d_in, const int* in_sizes, int n_in,
                              void* d_out, int out_size, void* d_ws, size_t ws_size,
                              hipStream_t stream)
{
    const float* hs      = (const float*)d_in[0];
    const int*   pos     = (const int*)  d_in[1];
    const float* patch_w = (const float*)d_in[3];
    const float* ln1_w   = (const float*)d_in[4];
    const float* ln1_b   = (const float*)d_in[5];
    const float* ln2_w   = (const float*)d_in[6];
    const float* ln2_b   = (const float*)d_in[7];
    const float* qkv_w   = (const float*)d_in[8];
    const float* qkv_b   = (const float*)d_in[9];
    const float* proj_w  = (const float*)d_in[10];
    const float* proj_b  = (const float*)d_in[11];
    const float* fc1_w   = (const float*)d_in[12];
    const float* fc1_b   = (const float*)d_in[13];
    const float* fc2_w   = (const float*)d_in[14];
    const float* fc2_b   = (const float*)d_in[15];
    const float* mln_w   = (const float*)d_in[16];
    const float* mln_b   = (const float*)d_in[17];
    const float* w1      = (const float*)d_in[18];
    const float* b1      = (const float*)d_in[19];
    const float* w2      = (const float*)d_in[20];
    const float* b2      = (const float*)d_in[21];
    float* out = (float*)d_out;

    char* p = (char*)d_ws;
    float*    x      = (float*)p;            p += (size_t)SEQ * EMBED * 4;
    float*    qkvbuf = (float*)p;            p += (size_t)SEQ * QKVN * 4;
    ushort_t* hbf    = (ushort_t*)p;         p += (size_t)SEQ * EMBED * 2;
    ushort_t* hsbf   = (ushort_t*)p;         p += (size_t)SEQ * PATCH_KP * 2;
    ushort_t* wbuf   = (ushort_t*)p;
    ushort_t* fc1out = (ushort_t*)qkvbuf;          // alias (qkv consumed pre-fc1)
    // q/k/v head-major buffers alias wbuf (weights idle during attention)
    ushort_t* qbv = wbuf;
    ushort_t* kbv = qbv + (size_t)HEADS * SEQ * 96;
    ushort_t* vtb = kbv + (size_t)HEADS * SEQ * 96;

    const dim3 tblk(32, 8);
    auto tgrid = [](int N, int Kp) { return dim3(N / 32, Kp / 32); };
    auto ggrid = [](int M, int N) { return dim3(N / 128, M / 128); };

    cast_hs<<<(SEQ * PATCH_KP + 255) / 256, 256, 0, stream>>>(hs, hsbf);
    transpose_cast<<<tgrid(EMBED, PATCH_KP), tblk, 0, stream>>>(
        patch_w, wbuf, PATCH_IN, EMBED, PATCH_KP);
    gemm_bf16<0, 0, 0><<<ggrid(SEQ, EMBED), 256, 0, stream>>>(
        hsbf, wbuf, nullptr, x, SEQ, EMBED, PATCH_KP);

    for (int i = 0; i < 2; ++i) {
        ln_f32<<<SEQ, 256, 0, stream>>>(x, ln1_w + i * EMBED, ln1_b + i * EMBED, hbf, EMBED);
        transpose_cast<<<tgrid(QKVN, EMBED), tblk, 0, stream>>>(
            qkv_w + (size_t)i * EMBED * QKVN, wbuf, EMBED, QKVN, EMBED);
        gemm_bf16<0, 0, 0><<<ggrid(SEQ, QKVN), 256, 0, stream>>>(
            hbf, wbuf, qkv_b + i * QKVN, qkvbuf, SEQ, QKVN, EMBED);
        rope_cast_qk<<<SEQ * HEADS * 48 / 256, 256, 0, stream>>>(qkvbuf, pos, qbv, kbv);
        v_transpose<<<HEADS * 80 * SEQ / 256, 256, 0, stream>>>(qkvbuf, vtb);
        attn_mfma<<<dim3(HEADS, NSEG, SEGLEN / 64), 256, 0, stream>>>(qbv, kbv, vtb, hbf);
        transpose_cast<<<tgrid(EMBED, EMBED), tblk, 0, stream>>>(
            proj_w + (size_t)i * EMBED * EMBED, wbuf, EMBED, EMBED, EMBED);
        gemm_bf16<0, 1, 0><<<ggrid(SEQ, EMBED), 256, 0, stream>>>(
            hbf, wbuf, proj_b + i * EMBED, x, SEQ, EMBED, EMBED);
        ln_f32<<<SEQ, 256, 0, stream>>>(x, ln2_w + i * EMBED, ln2_b + i * EMBED, hbf, EMBED);
        transpose_cast<<<tgrid(MLP, EMBED), tblk, 0, stream>>>(
            fc1_w + (size_t)i * EMBED * MLP, wbuf, EMBED, MLP, EMBED);
        gemm_bf16<1, 0, 1><<<ggrid(SEQ, MLP), 256, 0, stream>>>(
            hbf, wbuf, fc1_b + i * MLP, fc1out, SEQ, MLP, EMBED);
        transpose_cast<<<tgrid(EMBED, MLP), tblk, 0, stream>>>(
            fc2_w + (size_t)i * MLP * EMBED, wbuf, MLP, EMBED, MLP);
        gemm_bf16<0, 1, 0><<<ggrid(SEQ, EMBED), 256, 0, stream>>>(
            fc1out, wbuf, fc2_b + i * EMBED, x, SEQ, EMBED, MLP);
    }

    ln_f32<<<SEQ, 256, 0, stream>>>(x, mln_w, mln_b, hbf, EMBED);
    transpose_cast<<<tgrid(HIDDEN, 4 * EMBED), tblk, 0, stream>>>(
        w1, wbuf, 4 * EMBED, HIDDEN, 4 * EMBED);
    gemm_bf16<2, 0, 1><<<ggrid(MROWS, HIDDEN), 256, 0, stream>>>(
        hbf, wbuf, b1, fc1out, MROWS, HIDDEN, 4 * EMBED);
    transpose_cast<<<tgrid(HIDDEN, HIDDEN), tblk, 0, stream>>>(
        w2, wbuf, HIDDEN, HIDDEN, HIDDEN);
    gemm_bf16<0, 0, 0><<<ggrid(MROWS, HIDDEN), 256, 0, stream>>>(
        fc1out, wbuf, b2, out, MROWS, HIDDEN, HIDDEN);
}

// Round 4
// 943.148 us; speedup vs baseline: 11.8887x; 1.1607x over previous
//
#include <hip/hip_runtime.h>
#include <math.h>

#define SEQ    2048
#define EMBED  1280
#define HEADS  16
#define HD     80
#define MLP    5120
#define HIDDEN 3584
#define QKVN   3840
#define SEGLEN 1024
#define NSEG   2
#define PATCH_IN 1176
#define PATCH_KP 1216   // padded to mult of 64
#define MROWS  512

typedef __attribute__((ext_vector_type(8))) short bf16x8;
typedef __attribute__((ext_vector_type(4))) float f32x4;
typedef unsigned short ushort_t;

__device__ __forceinline__ ushort_t f2bf(float f) {
    unsigned u = __builtin_bit_cast(unsigned, f);
    unsigned r = u + 0x7FFFu + ((u >> 16) & 1u);   // RNE
    return (ushort_t)(r >> 16);
}

__device__ __forceinline__ void gld_lds16(const void* g, void* l) {
    __builtin_amdgcn_global_load_lds(
        (const __attribute__((address_space(1))) void*)g,
        (__attribute__((address_space(3))) void*)l, 16, 0, 0);
}

// ---------------------------------------------------------------------------
// bf16 MFMA GEMM, 2-phase double-buffered, BK=64, XOR-swizzled LDS.
// C = epi(A@Bt + bias) (+C if ACC). A:(M,K) bf16, Bt:(N,K) bf16.
// M,N mult of 128; K mult of 64. 256 thr = 4 waves, wave = 64x64 out.
// LDS stage: linear dest (gld_lds), PRE-SWIZZLED global source slot
// s^(r&7); read side applies same involution -> conflict-free ds_read_b128.
// ---------------------------------------------------------------------------
template<int EPI, int ACC, int OBF>
__global__ __launch_bounds__(256) void gemm_bf16(
    const ushort_t* __restrict__ A, const ushort_t* __restrict__ Bt,
    const float* __restrict__ bias, void* __restrict__ Cout,
    int M, int N, int K)
{
    __shared__ __align__(16) short Abuf[2][128 * 64];
    __shared__ __align__(16) short Bbuf[2][128 * 64];

    const int tid  = threadIdx.x;
    const int lane = tid & 63, wid = tid >> 6;
    const int wr = wid >> 1, wc = wid & 1;

    // T1: XCD-aware bijective swizzle (all call-site grids have nwg%8==0)
    const int nwg  = gridDim.x * gridDim.y;
    const int flat = blockIdx.y * gridDim.x + blockIdx.x;
    int bx, by;
    if (nwg & 7) { bx = blockIdx.x; by = blockIdx.y; }
    else {
        const int swz = (flat & 7) * (nwg >> 3) + (flat >> 3);
        bx = swz % gridDim.x; by = swz / gridDim.x;
    }
    const int row0 = by * 128, col0 = bx * 128;

    const int r0 = tid >> 3, s0 = tid & 7;      // staging row / 16B-slot
    const int lrow = lane & 15;
    const int lg = lane >> 4;
    const int rx = lrow & 7;                    // read-side swizzle key

    f32x4 acc[4][4] = {};

    auto stage = [&](int buf, int k0) {
        #pragma unroll
        for (int i = 0; i < 4; ++i) {
            const int r = r0 + i * 32;
            const int ksl = (s0 ^ (r & 7)) * 8;      // pre-swizzled source slot
            gld_lds16(A  + (size_t)(row0 + r) * K + k0 + ksl,
                      &Abuf[buf][(tid + i * 256) * 8]);
            gld_lds16(Bt + (size_t)(col0 + r) * K + k0 + ksl,
                      &Bbuf[buf][(tid + i * 256) * 8]);
        }
    };

    const int nt = K >> 6;
    stage(0, 0);
    __syncthreads();                             // vmcnt(0)+barrier (compiler drain)

    int cur = 0;
    for (int t = 0; t < nt; ++t) {
        if (t + 1 < nt) stage(cur ^ 1, (t + 1) << 6);   // prefetch overlaps MFMA

        #pragma unroll
        for (int ko = 0; ko < 2; ++ko) {
            bf16x8 a[4], b[4];
            const int ts = ((ko * 4 + lg) ^ rx) * 8;    // swizzled read slot
            #pragma unroll
            for (int m = 0; m < 4; ++m)
                a[m] = *(const bf16x8*)&Abuf[cur][(wr * 64 + m * 16 + lrow) * 64 + ts];
            #pragma unroll
            for (int n = 0; n < 4; ++n)
                b[n] = *(const bf16x8*)&Bbuf[cur][(wc * 64 + n * 16 + lrow) * 64 + ts];
            #pragma unroll
            for (int m = 0; m < 4; ++m)
                #pragma unroll
                for (int n = 0; n < 4; ++n)
                    acc[m][n] = __builtin_amdgcn_mfma_f32_16x16x32_bf16(
                        a[m], b[n], acc[m][n], 0, 0, 0);
        }
        __syncthreads();                         // drains prefetch vmcnt + lgkm
        cur ^= 1;
    }

    // epilogue: C/D layout col = lane&15, row = (lane>>4)*4 + reg
    const int rbase = lg * 4;
    #pragma unroll
    for (int n = 0; n < 4; ++n) {
        const int c = col0 + wc * 64 + n * 16 + lrow;
        const float bv = bias ? bias[c] : 0.f;
        #pragma unroll
        for (int m = 0; m < 4; ++m) {
            const int rb = row0 + wr * 64 + m * 16 + rbase;
            #pragma unroll
            for (int g = 0; g < 4; ++g) {
                float v = acc[m][n][g] + bv;
                if (EPI == 1) v = v / (1.f + expf(-v));
                if (EPI == 2) v = 0.5f * v * (1.f + erff(v * 0.70710678f));
                const size_t idx = (size_t)(rb + g) * N + c;
                if (OBF) {
                    ((ushort_t*)Cout)[idx] = f2bf(v);
                } else {
                    float* Cf = (float*)Cout;
                    if (ACC) v += Cf[idx];
                    Cf[idx] = v;
                }
            }
        }
    }
}

// ---------------------------------------------------------------------------
// transpose + cast (unchanged)
// ---------------------------------------------------------------------------
__global__ __launch_bounds__(256) void transpose_cast(
    const float* __restrict__ in, ushort_t* __restrict__ out, int K, int N, int Kp)
{
    __shared__ float t[32][33];
    const int n0 = blockIdx.x * 32, k0 = blockIdx.y * 32;
    const int tx = threadIdx.x, ty = threadIdx.y;
    #pragma unroll
    for (int j = 0; j < 4; ++j) {
        int k = k0 + ty + j * 8;
        t[ty + j * 8][tx] = (k < K) ? in[(size_t)k * N + n0 + tx] : 0.f;
    }
    __syncthreads();
    #pragma unroll
    for (int j = 0; j < 4; ++j) {
        int n = n0 + ty + j * 8;
        out[(size_t)n * Kp + k0 + tx] = f2bf(t[tx][ty + j * 8]);
    }
}

__global__ __launch_bounds__(256) void cast_hs(
    const float* __restrict__ in, ushort_t* __restrict__ out)
{
    int idx = blockIdx.x * 256 + threadIdx.x;
    if (idx >= SEQ * PATCH_KP) return;
    int s = idx / PATCH_KP, k = idx % PATCH_KP;
    out[idx] = (k < PATCH_IN) ? f2bf(in[(size_t)s * PATCH_IN + k]) : 0;
}

// ---------------------------------------------------------------------------
// LayerNorm (unchanged)
// ---------------------------------------------------------------------------
__global__ __launch_bounds__(256) void ln_f32(
    const float* __restrict__ x, const float* __restrict__ w,
    const float* __restrict__ b, ushort_t* __restrict__ y, int D)
{
    const int row = blockIdx.x;
    const float* xr = x + (size_t)row * D;
    float s = 0.f, ss = 0.f;
    for (int d = threadIdx.x; d < D; d += 256) {
        float v = xr[d];
        s += v; ss = fmaf(v, v, ss);
    }
    __shared__ float red[2][4];
    const int lane = threadIdx.x & 63, wid = threadIdx.x >> 6;
    #pragma unroll
    for (int off = 32; off; off >>= 1) {
        s  += __shfl_xor(s,  off);
        ss += __shfl_xor(ss, off);
    }
    if (lane == 0) { red[0][wid] = s; red[1][wid] = ss; }
    __syncthreads();
    s  = red[0][0] + red[0][1] + red[0][2] + red[0][3];
    ss = red[1][0] + red[1][1] + red[1][2] + red[1][3];
    const float mu  = s / D;
    const float var = ss / D - mu * mu;
    const float inv = rsqrtf(var + 1e-6f);
    ushort_t* yr = y + (size_t)row * D;
    for (int d = threadIdx.x; d < D; d += 256)
        yr[d] = f2bf((xr[d] - mu) * inv * w[d] + b[d]);
}

// ---------------------------------------------------------------------------
// RoPE + scale + bf16 cast + head-major relayout (unchanged)
// ---------------------------------------------------------------------------
__global__ __launch_bounds__(256) void rope_cast_qk(
    const float* __restrict__ qkv, const int* __restrict__ pos,
    ushort_t* __restrict__ qb, ushort_t* __restrict__ kb)
{
    int idx = blockIdx.x * 256 + threadIdx.x;
    const int j = idx % 48;
    const int h = (idx / 48) % HEADS;
    const int s = idx / (48 * HEADS);
    if (s >= SEQ) return;
    const size_t ob = ((size_t)h * SEQ + s) * 96;
    if (j >= 40) {
        qb[ob + 40 + j] = 0; qb[ob + 48 + j] = 0;
        kb[ob + 40 + j] = 0; kb[ob + 48 + j] = 0;
        return;
    }
    const float p = (float)pos[s * 2 + (j / 20)];
    const float f = p * powf(10000.f, -(float)(j % 20) / 20.f);
    float c, sn;
    sincosf(f, &c, &sn);
    const float* q = qkv + (size_t)s * QKVN + h * HD;
    const float* k = q + EMBED;
    const float scale = 0.11180339887498949f;
    float q1 = q[j], q2 = q[j + 40];
    qb[ob + j]      = f2bf((q1 * c - q2 * sn) * scale);
    qb[ob + j + 40] = f2bf((q2 * c + q1 * sn) * scale);
    float k1 = k[j], k2 = k[j + 40];
    kb[ob + j]      = f2bf(k1 * c - k2 * sn);
    kb[ob + j + 40] = f2bf(k2 * c + k1 * sn);
}

__global__ __launch_bounds__(256) void v_transpose(
    const float* __restrict__ qkv, ushort_t* __restrict__ vtb)
{
    int idx = blockIdx.x * 256 + threadIdx.x;
    int s = idx & (SEQ - 1);
    int d = (idx >> 11) % 80;
    int h = idx / (SEQ * 80);
    if (h >= HEADS) return;
    vtb[((size_t)h * 80 + d) * SEQ + s] =
        f2bf(qkv[(size_t)s * QKVN + 2 * EMBED + h * HD + d]);
}

// ---------------------------------------------------------------------------
// MFMA flash attention (unchanged)
// ---------------------------------------------------------------------------
#define AKC  64
#define KSTR 104
#define VSTR 72
#define PSTR 72

__global__ __launch_bounds__(256) void attn_mfma(
    const ushort_t* __restrict__ qb, const ushort_t* __restrict__ kb,
    const ushort_t* __restrict__ vtb, ushort_t* __restrict__ out)
{
    const int hh = blockIdx.x;
    const int seg = blockIdx.y;
    const int tid = threadIdx.x, lane = tid & 63, wid = tid >> 6;
    const int lr = lane & 15, lg = lane >> 4;

    __shared__ __align__(16) short Ks[AKC * KSTR];
    __shared__ __align__(16) short Vs[80 * VSTR];
    __shared__ __align__(16) short Ps[4][16 * PSTR];

    const int sq = seg * SEGLEN;
    const int qrow0 = sq + blockIdx.z * 64 + wid * 16;

    bf16x8 qf[3];
    #pragma unroll
    for (int f = 0; f < 3; ++f)
        qf[f] = *(const bf16x8*)&qb[((size_t)hh * SEQ + qrow0 + lr) * 96 + f * 32 + lg * 8];

    f32x4 o[5] = {};
    float m[4], l[4];
    #pragma unroll
    for (int g = 0; g < 4; ++g) { m[g] = -1e30f; l[g] = 0.f; }

    for (int c0 = 0; c0 < SEGLEN; c0 += AKC) {
        __syncthreads();
        #pragma unroll
        for (int i = 0; i < 3; ++i) {
            int id = tid + i * 256;
            int r = id / 12, s = id % 12;
            *(bf16x8*)&Ks[r * KSTR + s * 8] =
                *(const bf16x8*)&kb[((size_t)hh * SEQ + sq + c0 + r) * 96 + s * 8];
        }
        #pragma unroll
        for (int i = 0; i < 3; ++i) {
            int id = tid + i * 256;
            if (id < 640) {
                int d = id / 8, s = id % 8;
                *(bf16x8*)&Vs[d * VSTR + s * 8] =
                    *(const bf16x8*)&vtb[((size_t)hh * 80 + d) * SEQ + sq + c0 + s * 8];
            }
        }
        __syncthreads();

        f32x4 sc[4] = {};
        #pragma unroll
        for (int kt = 0; kt < 4; ++kt)
            #pragma unroll
            for (int f = 0; f < 3; ++f) {
                bf16x8 kf = *(const bf16x8*)&Ks[(kt * 16 + lr) * KSTR + f * 32 + lg * 8];
                sc[kt] = __builtin_amdgcn_mfma_f32_16x16x32_bf16(qf[f], kf, sc[kt], 0, 0, 0);
            }

        float corr[4], ps[4];
        #pragma unroll
        for (int g = 0; g < 4; ++g) {
            float v = fmaxf(fmaxf(sc[0][g], sc[1][g]), fmaxf(sc[2][g], sc[3][g]));
            v = fmaxf(v, __shfl_xor(v, 1));
            v = fmaxf(v, __shfl_xor(v, 2));
            v = fmaxf(v, __shfl_xor(v, 4));
            v = fmaxf(v, __shfl_xor(v, 8));
            const float mn = fmaxf(m[g], v);
            corr[g] = __expf(m[g] - mn);
            m[g] = mn;
            ps[g] = 0.f;
        }
        #pragma unroll
        for (int kt = 0; kt < 4; ++kt)
            #pragma unroll
            for (int g = 0; g < 4; ++g) {
                float p = __expf(sc[kt][g] - m[g]);
                ps[g] += p;
                Ps[wid][(lg * 4 + g) * PSTR + kt * 16 + lr] = f2bf(p);
            }
        #pragma unroll
        for (int g = 0; g < 4; ++g) {
            float rs = ps[g];
            rs += __shfl_xor(rs, 1);
            rs += __shfl_xor(rs, 2);
            rs += __shfl_xor(rs, 4);
            rs += __shfl_xor(rs, 8);
            l[g] = l[g] * corr[g] + rs;
        }
        #pragma unroll
        for (int n = 0; n < 5; ++n)
            #pragma unroll
            for (int g = 0; g < 4; ++g) o[n][g] *= corr[g];

        #pragma unroll
        for (int jf = 0; jf < 2; ++jf) {
            bf16x8 pa = *(const bf16x8*)&Ps[wid][lr * PSTR + jf * 32 + lg * 8];
            #pragma unroll
            for (int n = 0; n < 5; ++n) {
                bf16x8 vf = *(const bf16x8*)&Vs[(n * 16 + lr) * VSTR + jf * 32 + lg * 8];
                o[n] = __builtin_amdgcn_mfma_f32_16x16x32_bf16(pa, vf, o[n], 0, 0, 0);
            }
        }
    }

    #pragma unroll
    for (int g = 0; g < 4; ++g) {
        const float inv = 1.f / l[g];
        const int r = qrow0 + lg * 4 + g;
        #pragma unroll
        for (int n = 0; n < 5; ++n)
            out[(size_t)r * EMBED + hh * HD + n * 16 + lr] = f2bf(o[n][g] * inv);
    }
}

// ---------------------------------------------------------------------------

extern "C" void kernel_launch(void* const* d_in, const int* in_sizes, int n_in,
                              void* d_out, int out_size, void* d_ws, size_t ws_size,
                              hipStream_t stream)
{
    const float* hs      = (const float*)d_in[0];
    const int*   pos     = (const int*)  d_in[1];
    const float* patch_w = (const float*)d_in[3];
    const float* ln1_w   = (const float*)d_in[4];
    const float* ln1_b   = (const float*)d_in[5];
    const float* ln2_w   = (const float*)d_in[6];
    const float* ln2_b   = (const float*)d_in[7];
    const float* qkv_w   = (const float*)d_in[8];
    const float* qkv_b   = (const float*)d_in[9];
    const float* proj_w  = (const float*)d_in[10];
    const float* proj_b  = (const float*)d_in[11];
    const float* fc1_w   = (const float*)d_in[12];
    const float* fc1_b   = (const float*)d_in[13];
    const float* fc2_w   = (const float*)d_in[14];
    const float* fc2_b   = (const float*)d_in[15];
    const float* mln_w   = (const float*)d_in[16];
    const float* mln_b   = (const float*)d_in[17];
    const float* w1      = (const float*)d_in[18];
    const float* b1      = (const float*)d_in[19];
    const float* w2      = (const float*)d_in[20];
    const float* b2      = (const float*)d_in[21];
    float* out = (float*)d_out;

    char* p = (char*)d_ws;
    float*    x      = (float*)p;            p += (size_t)SEQ * EMBED * 4;
    float*    qkvbuf = (float*)p;            p += (size_t)SEQ * QKVN * 4;
    ushort_t* hbf    = (ushort_t*)p;         p += (size_t)SEQ * EMBED * 2;
    ushort_t* hsbf   = (ushort_t*)p;         p += (size_t)SEQ * PATCH_KP * 2;
    ushort_t* wbuf   = (ushort_t*)p;
    ushort_t* fc1out = (ushort_t*)qkvbuf;
    ushort_t* qbv = wbuf;
    ushort_t* kbv = qbv + (size_t)HEADS * SEQ * 96;
    ushort_t* vtb = kbv + (size_t)HEADS * SEQ * 96;

    const dim3 tblk(32, 8);
    auto tgrid = [](int N, int Kp) { return dim3(N / 32, Kp / 32); };
    auto ggrid = [](int M, int N) { return dim3(N / 128, M / 128); };

    cast_hs<<<(SEQ * PATCH_KP + 255) / 256, 256, 0, stream>>>(hs, hsbf);
    transpose_cast<<<tgrid(EMBED, PATCH_KP), tblk, 0, stream>>>(
        patch_w, wbuf, PATCH_IN, EMBED, PATCH_KP);
    gemm_bf16<0, 0, 0><<<ggrid(SEQ, EMBED), 256, 0, stream>>>(
        hsbf, wbuf, nullptr, x, SEQ, EMBED, PATCH_KP);

    for (int i = 0; i < 2; ++i) {
        ln_f32<<<SEQ, 256, 0, stream>>>(x, ln1_w + i * EMBED, ln1_b + i * EMBED, hbf, EMBED);
        transpose_cast<<<tgrid(QKVN, EMBED), tblk, 0, stream>>>(
            qkv_w + (size_t)i * EMBED * QKVN, wbuf, EMBED, QKVN, EMBED);
        gemm_bf16<0, 0, 0><<<ggrid(SEQ, QKVN), 256, 0, stream>>>(
            hbf, wbuf, qkv_b + i * QKVN, qkvbuf, SEQ, QKVN, EMBED);
        rope_cast_qk<<<SEQ * HEADS * 48 / 256, 256, 0, stream>>>(qkvbuf, pos, qbv, kbv);
        v_transpose<<<HEADS * 80 * SEQ / 256, 256, 0, stream>>>(qkvbuf, vtb);
        attn_mfma<<<dim3(HEADS, NSEG, SEGLEN / 64), 256, 0, stream>>>(qbv, kbv, vtb, hbf);
        transpose_cast<<<tgrid(EMBED, EMBED), tblk, 0, stream>>>(
            proj_w + (size_t)i * EMBED * EMBED, wbuf, EMBED, EMBED, EMBED);
        gemm_bf16<0, 1, 0><<<ggrid(SEQ, EMBED), 256, 0, stream>>>(
            hbf, wbuf, proj_b + i * EMBED, x, SEQ, EMBED, EMBED);
        ln_f32<<<SEQ, 256, 0, stream>>>(x, ln2_w + i * EMBED, ln2_b + i * EMBED, hbf, EMBED);
        transpose_cast<<<tgrid(MLP, EMBED), tblk, 0, stream>>>(
            fc1_w + (size_t)i * EMBED * MLP, wbuf, EMBED, MLP, EMBED);
        gemm_bf16<1, 0, 1><<<ggrid(SEQ, MLP), 256, 0, stream>>>(
            hbf, wbuf, fc1_b + i * MLP, fc1out, SEQ, MLP, EMBED);
        transpose_cast<<<tgrid(EMBED, MLP), tblk, 0, stream>>>(
            fc2_w + (size_t)i * MLP * EMBED, wbuf, MLP, EMBED, MLP);
        gemm_bf16<0, 1, 0><<<ggrid(SEQ, EMBED), 256, 0, stream>>>(
            fc1out, wbuf, fc2_b + i * EMBED, x, SEQ, EMBED, MLP);
    }

    ln_f32<<<SEQ, 256, 0, stream>>>(x, mln_w, mln_b, hbf, EMBED);
    transpose_cast<<<tgrid(HIDDEN, 4 * EMBED), tblk, 0, stream>>>(
        w1, wbuf, 4 * EMBED, HIDDEN, 4 * EMBED);
    gemm_bf16<2, 0, 1><<<ggrid(MROWS, HIDDEN), 256, 0, stream>>>(
        hbf, wbuf, b1, fc1out, MROWS, HIDDEN, 4 * EMBED);
    transpose_cast<<<tgrid(HIDDEN, HIDDEN), tblk, 0, stream>>>(
        w2, wbuf, HIDDEN, HIDDEN, HIDDEN);
    gemm_bf16<0, 0, 0><<<ggrid(MROWS, HIDDEN), 256, 0, stream>>>(
        fc1out, wbuf, b2, out, MROWS, HIDDEN, HIDDEN);
}

// Round 5
// 838.937 us; speedup vs baseline: 13.3655x; 1.1242x over previous
//
#include <hip/hip_runtime.h>
#include <math.h>

#define SEQ    2048
#define EMBED  1280
#define HEADS  16
#define HD     80
#define MLP    5120
#define HIDDEN 3584
#define QKVN   3840
#define SEGLEN 1024
#define NSEG   2
#define PATCH_IN 1176
#define PATCH_KP 1216   // padded to mult of 64
#define MROWS  512

typedef __attribute__((ext_vector_type(8))) short bf16x8;
typedef __attribute__((ext_vector_type(4))) float f32x4;
typedef unsigned short ushort_t;

__device__ __forceinline__ ushort_t f2bf(float f) {
    unsigned u = __builtin_bit_cast(unsigned, f);
    unsigned r = u + 0x7FFFu + ((u >> 16) & 1u);   // RNE
    return (ushort_t)(r >> 16);
}

__device__ __forceinline__ void gld_lds16(const void* g, void* l) {
    __builtin_amdgcn_global_load_lds(
        (const __attribute__((address_space(1))) void*)g,
        (__attribute__((address_space(3))) void*)l, 16, 0, 0);
}

// ---------------------------------------------------------------------------
// bf16 MFMA GEMM, BK=64 double-buffered with COUNTED vmcnt pipeline (T4).
// C = epi(A@Bt + bias) (+C if ACC). A:(M,K) bf16, Bt:(N,K) bf16.
// M,N mult of 128; K mult of 64, K>=128. 256 thr = 4 waves, wave = 64x64.
// Per K-step: vmcnt(8) [keep next tile's 8 loads IN FLIGHT across barrier]
// -> barrier -> ds_read frags to regs -> lgkmcnt(0) -> barrier ->
// stage(t+2) -> 32 MFMA. Loads get ~2 steps of latency cover.
// ---------------------------------------------------------------------------
template<int EPI, int ACC, int OBF>
__global__ __launch_bounds__(256) void gemm_bf16(
    const ushort_t* __restrict__ A, const ushort_t* __restrict__ Bt,
    const float* __restrict__ bias, void* __restrict__ Cout,
    int M, int N, int K)
{
    __shared__ __align__(16) short Abuf[2][128 * 64];
    __shared__ __align__(16) short Bbuf[2][128 * 64];

    const int tid  = threadIdx.x;
    const int lane = tid & 63, wid = tid >> 6;
    const int wr = wid >> 1, wc = wid & 1;

    // T1: XCD-aware bijective swizzle (all call-site grids have nwg%8==0)
    const int nwg  = gridDim.x * gridDim.y;
    const int flat = blockIdx.y * gridDim.x + blockIdx.x;
    int bx, by;
    if (nwg & 7) { bx = blockIdx.x; by = blockIdx.y; }
    else {
        const int swz = (flat & 7) * (nwg >> 3) + (flat >> 3);
        bx = swz % gridDim.x; by = swz / gridDim.x;
    }
    const int row0 = by * 128, col0 = bx * 128;

    const int r0 = tid >> 3, s0 = tid & 7;      // staging row / 16B-slot
    const int lrow = lane & 15;
    const int lg = lane >> 4;
    const int rx = lrow & 7;                    // read-side swizzle key

    f32x4 acc[4][4] = {};

    auto stage = [&](int buf, int t) {
        const int k0 = t << 6;
        #pragma unroll
        for (int i = 0; i < 4; ++i) {
            const int r = r0 + i * 32;
            const int ksl = (s0 ^ (r & 7)) * 8;      // pre-swizzled source slot
            gld_lds16(A  + (size_t)(row0 + r) * K + k0 + ksl,
                      &Abuf[buf][(tid + i * 256) * 8]);
            gld_lds16(Bt + (size_t)(col0 + r) * K + k0 + ksl,
                      &Bbuf[buf][(tid + i * 256) * 8]);
        }
    };

    const int nt = K >> 6;                       // always >= 2 at our shapes
    stage(0, 0);
    stage(1, 1);                                 // 16 loads in flight

    int cur = 0;
    for (int t = 0; t < nt; ++t) {
        // wait ONLY for buf[cur]'s 8 loads; keep the next 8 in flight
        if (t < nt - 1) { asm volatile("s_waitcnt vmcnt(8)" ::: "memory"); }
        else            { asm volatile("s_waitcnt vmcnt(0)" ::: "memory"); }
        __builtin_amdgcn_s_barrier();            // all waves' cur-loads landed

        bf16x8 a[2][4], b[2][4];
        #pragma unroll
        for (int ko = 0; ko < 2; ++ko) {
            const int ts = ((ko * 4 + lg) ^ rx) * 8;    // swizzled read slot
            #pragma unroll
            for (int m = 0; m < 4; ++m)
                a[ko][m] = *(const bf16x8*)&Abuf[cur][(wr * 64 + m * 16 + lrow) * 64 + ts];
            #pragma unroll
            for (int n = 0; n < 4; ++n)
                b[ko][n] = *(const bf16x8*)&Bbuf[cur][(wc * 64 + n * 16 + lrow) * 64 + ts];
        }
        asm volatile("s_waitcnt lgkmcnt(0)" ::: "memory");   // frags in regs
        __builtin_amdgcn_s_barrier();            // all waves done READING cur
        __builtin_amdgcn_sched_barrier(0);       // pin stage below the barrier

        if (t + 2 < nt) stage(cur, t + 2);       // overwrite cur for t+2

        #pragma unroll
        for (int ko = 0; ko < 2; ++ko)
            #pragma unroll
            for (int m = 0; m < 4; ++m)
                #pragma unroll
                for (int n = 0; n < 4; ++n)
                    acc[m][n] = __builtin_amdgcn_mfma_f32_16x16x32_bf16(
                        a[ko][m], b[ko][n], acc[m][n], 0, 0, 0);
        cur ^= 1;
    }

    // epilogue: C/D layout col = lane&15, row = (lane>>4)*4 + reg
    const int rbase = lg * 4;
    #pragma unroll
    for (int n = 0; n < 4; ++n) {
        const int c = col0 + wc * 64 + n * 16 + lrow;
        const float bv = bias ? bias[c] : 0.f;
        #pragma unroll
        for (int m = 0; m < 4; ++m) {
            const int rb = row0 + wr * 64 + m * 16 + rbase;
            #pragma unroll
            for (int g = 0; g < 4; ++g) {
                float v = acc[m][n][g] + bv;
                if (EPI == 1) v = v / (1.f + expf(-v));
                if (EPI == 2) v = 0.5f * v * (1.f + erff(v * 0.70710678f));
                const size_t idx = (size_t)(rb + g) * N + c;
                if (OBF) {
                    ((ushort_t*)Cout)[idx] = f2bf(v);
                } else {
                    float* Cf = (float*)Cout;
                    if (ACC) v += Cf[idx];
                    Cf[idx] = v;
                }
            }
        }
    }
}

// ---------------------------------------------------------------------------
// transpose + cast (unchanged)
// ---------------------------------------------------------------------------
__global__ __launch_bounds__(256) void transpose_cast(
    const float* __restrict__ in, ushort_t* __restrict__ out, int K, int N, int Kp)
{
    __shared__ float t[32][33];
    const int n0 = blockIdx.x * 32, k0 = blockIdx.y * 32;
    const int tx = threadIdx.x, ty = threadIdx.y;
    #pragma unroll
    for (int j = 0; j < 4; ++j) {
        int k = k0 + ty + j * 8;
        t[ty + j * 8][tx] = (k < K) ? in[(size_t)k * N + n0 + tx] : 0.f;
    }
    __syncthreads();
    #pragma unroll
    for (int j = 0; j < 4; ++j) {
        int n = n0 + ty + j * 8;
        out[(size_t)n * Kp + k0 + tx] = f2bf(t[tx][ty + j * 8]);
    }
}

__global__ __launch_bounds__(256) void cast_hs(
    const float* __restrict__ in, ushort_t* __restrict__ out)
{
    int idx = blockIdx.x * 256 + threadIdx.x;
    if (idx >= SEQ * PATCH_KP) return;
    int s = idx / PATCH_KP, k = idx % PATCH_KP;
    out[idx] = (k < PATCH_IN) ? f2bf(in[(size_t)s * PATCH_IN + k]) : 0;
}

// ---------------------------------------------------------------------------
// LayerNorm (unchanged)
// ---------------------------------------------------------------------------
__global__ __launch_bounds__(256) void ln_f32(
    const float* __restrict__ x, const float* __restrict__ w,
    const float* __restrict__ b, ushort_t* __restrict__ y, int D)
{
    const int row = blockIdx.x;
    const float* xr = x + (size_t)row * D;
    float s = 0.f, ss = 0.f;
    for (int d = threadIdx.x; d < D; d += 256) {
        float v = xr[d];
        s += v; ss = fmaf(v, v, ss);
    }
    __shared__ float red[2][4];
    const int lane = threadIdx.x & 63, wid = threadIdx.x >> 6;
    #pragma unroll
    for (int off = 32; off; off >>= 1) {
        s  += __shfl_xor(s,  off);
        ss += __shfl_xor(ss, off);
    }
    if (lane == 0) { red[0][wid] = s; red[1][wid] = ss; }
    __syncthreads();
    s  = red[0][0] + red[0][1] + red[0][2] + red[0][3];
    ss = red[1][0] + red[1][1] + red[1][2] + red[1][3];
    const float mu  = s / D;
    const float var = ss / D - mu * mu;
    const float inv = rsqrtf(var + 1e-6f);
    ushort_t* yr = y + (size_t)row * D;
    for (int d = threadIdx.x; d < D; d += 256)
        yr[d] = f2bf((xr[d] - mu) * inv * w[d] + b[d]);
}

// ---------------------------------------------------------------------------
// RoPE + scale + bf16 cast + head-major relayout (unchanged)
// ---------------------------------------------------------------------------
__global__ __launch_bounds__(256) void rope_cast_qk(
    const float* __restrict__ qkv, const int* __restrict__ pos,
    ushort_t* __restrict__ qb, ushort_t* __restrict__ kb)
{
    int idx = blockIdx.x * 256 + threadIdx.x;
    const int j = idx % 48;
    const int h = (idx / 48) % HEADS;
    const int s = idx / (48 * HEADS);
    if (s >= SEQ) return;
    const size_t ob = ((size_t)h * SEQ + s) * 96;
    if (j >= 40) {
        qb[ob + 40 + j] = 0; qb[ob + 48 + j] = 0;
        kb[ob + 40 + j] = 0; kb[ob + 48 + j] = 0;
        return;
    }
    const float p = (float)pos[s * 2 + (j / 20)];
    const float f = p * powf(10000.f, -(float)(j % 20) / 20.f);
    float c, sn;
    sincosf(f, &c, &sn);
    const float* q = qkv + (size_t)s * QKVN + h * HD;
    const float* k = q + EMBED;
    const float scale = 0.11180339887498949f;
    float q1 = q[j], q2 = q[j + 40];
    qb[ob + j]      = f2bf((q1 * c - q2 * sn) * scale);
    qb[ob + j + 40] = f2bf((q2 * c + q1 * sn) * scale);
    float k1 = k[j], k2 = k[j + 40];
    kb[ob + j]      = f2bf(k1 * c - k2 * sn);
    kb[ob + j + 40] = f2bf(k2 * c + k1 * sn);
}

__global__ __launch_bounds__(256) void v_transpose(
    const float* __restrict__ qkv, ushort_t* __restrict__ vtb)
{
    int idx = blockIdx.x * 256 + threadIdx.x;
    int s = idx & (SEQ - 1);
    int d = (idx >> 11) % 80;
    int h = idx / (SEQ * 80);
    if (h >= HEADS) return;
    vtb[((size_t)h * 80 + d) * SEQ + s] =
        f2bf(qkv[(size_t)s * QKVN + 2 * EMBED + h * HD + d]);
}

// ---------------------------------------------------------------------------
// MFMA flash attention (unchanged)
// ---------------------------------------------------------------------------
#define AKC  64
#define KSTR 104
#define VSTR 72
#define PSTR 72

__global__ __launch_bounds__(256) void attn_mfma(
    const ushort_t* __restrict__ qb, const ushort_t* __restrict__ kb,
    const ushort_t* __restrict__ vtb, ushort_t* __restrict__ out)
{
    const int hh = blockIdx.x;
    const int seg = blockIdx.y;
    const int tid = threadIdx.x, lane = tid & 63, wid = tid >> 6;
    const int lr = lane & 15, lg = lane >> 4;

    __shared__ __align__(16) short Ks[AKC * KSTR];
    __shared__ __align__(16) short Vs[80 * VSTR];
    __shared__ __align__(16) short Ps[4][16 * PSTR];

    const int sq = seg * SEGLEN;
    const int qrow0 = sq + blockIdx.z * 64 + wid * 16;

    bf16x8 qf[3];
    #pragma unroll
    for (int f = 0; f < 3; ++f)
        qf[f] = *(const bf16x8*)&qb[((size_t)hh * SEQ + qrow0 + lr) * 96 + f * 32 + lg * 8];

    f32x4 o[5] = {};
    float m[4], l[4];
    #pragma unroll
    for (int g = 0; g < 4; ++g) { m[g] = -1e30f; l[g] = 0.f; }

    for (int c0 = 0; c0 < SEGLEN; c0 += AKC) {
        __syncthreads();
        #pragma unroll
        for (int i = 0; i < 3; ++i) {
            int id = tid + i * 256;
            int r = id / 12, s = id % 12;
            *(bf16x8*)&Ks[r * KSTR + s * 8] =
                *(const bf16x8*)&kb[((size_t)hh * SEQ + sq + c0 + r) * 96 + s * 8];
        }
        #pragma unroll
        for (int i = 0; i < 3; ++i) {
            int id = tid + i * 256;
            if (id < 640) {
                int d = id / 8, s = id % 8;
                *(bf16x8*)&Vs[d * VSTR + s * 8] =
                    *(const bf16x8*)&vtb[((size_t)hh * 80 + d) * SEQ + sq + c0 + s * 8];
            }
        }
        __syncthreads();

        f32x4 sc[4] = {};
        #pragma unroll
        for (int kt = 0; kt < 4; ++kt)
            #pragma unroll
            for (int f = 0; f < 3; ++f) {
                bf16x8 kf = *(const bf16x8*)&Ks[(kt * 16 + lr) * KSTR + f * 32 + lg * 8];
                sc[kt] = __builtin_amdgcn_mfma_f32_16x16x32_bf16(qf[f], kf, sc[kt], 0, 0, 0);
            }

        float corr[4], ps[4];
        #pragma unroll
        for (int g = 0; g < 4; ++g) {
            float v = fmaxf(fmaxf(sc[0][g], sc[1][g]), fmaxf(sc[2][g], sc[3][g]));
            v = fmaxf(v, __shfl_xor(v, 1));
            v = fmaxf(v, __shfl_xor(v, 2));
            v = fmaxf(v, __shfl_xor(v, 4));
            v = fmaxf(v, __shfl_xor(v, 8));
            const float mn = fmaxf(m[g], v);
            corr[g] = __expf(m[g] - mn);
            m[g] = mn;
            ps[g] = 0.f;
        }
        #pragma unroll
        for (int kt = 0; kt < 4; ++kt)
            #pragma unroll
            for (int g = 0; g < 4; ++g) {
                float p = __expf(sc[kt][g] - m[g]);
                ps[g] += p;
                Ps[wid][(lg * 4 + g) * PSTR + kt * 16 + lr] = f2bf(p);
            }
        #pragma unroll
        for (int g = 0; g < 4; ++g) {
            float rs = ps[g];
            rs += __shfl_xor(rs, 1);
            rs += __shfl_xor(rs, 2);
            rs += __shfl_xor(rs, 4);
            rs += __shfl_xor(rs, 8);
            l[g] = l[g] * corr[g] + rs;
        }
        #pragma unroll
        for (int n = 0; n < 5; ++n)
            #pragma unroll
            for (int g = 0; g < 4; ++g) o[n][g] *= corr[g];

        #pragma unroll
        for (int jf = 0; jf < 2; ++jf) {
            bf16x8 pa = *(const bf16x8*)&Ps[wid][lr * PSTR + jf * 32 + lg * 8];
            #pragma unroll
            for (int n = 0; n < 5; ++n) {
                bf16x8 vf = *(const bf16x8*)&Vs[(n * 16 + lr) * VSTR + jf * 32 + lg * 8];
                o[n] = __builtin_amdgcn_mfma_f32_16x16x32_bf16(pa, vf, o[n], 0, 0, 0);
            }
        }
    }

    #pragma unroll
    for (int g = 0; g < 4; ++g) {
        const float inv = 1.f / l[g];
        const int r = qrow0 + lg * 4 + g;
        #pragma unroll
        for (int n = 0; n < 5; ++n)
            out[(size_t)r * EMBED + hh * HD + n * 16 + lr] = f2bf(o[n][g] * inv);
    }
}

// ---------------------------------------------------------------------------

extern "C" void kernel_launch(void* const* d_in, const int* in_sizes, int n_in,
                              void* d_out, int out_size, void* d_ws, size_t ws_size,
                              hipStream_t stream)
{
    const float* hs      = (const float*)d_in[0];
    const int*   pos     = (const int*)  d_in[1];
    const float* patch_w = (const float*)d_in[3];
    const float* ln1_w   = (const float*)d_in[4];
    const float* ln1_b   = (const float*)d_in[5];
    const float* ln2_w   = (const float*)d_in[6];
    const float* ln2_b   = (const float*)d_in[7];
    const float* qkv_w   = (const float*)d_in[8];
    const float* qkv_b   = (const float*)d_in[9];
    const float* proj_w  = (const float*)d_in[10];
    const float* proj_b  = (const float*)d_in[11];
    const float* fc1_w   = (const float*)d_in[12];
    const float* fc1_b   = (const float*)d_in[13];
    const float* fc2_w   = (const float*)d_in[14];
    const float* fc2_b   = (const float*)d_in[15];
    const float* mln_w   = (const float*)d_in[16];
    const float* mln_b   = (const float*)d_in[17];
    const float* w1      = (const float*)d_in[18];
    const float* b1      = (const float*)d_in[19];
    const float* w2      = (const float*)d_in[20];
    const float* b2      = (const float*)d_in[21];
    float* out = (float*)d_out;

    char* p = (char*)d_ws;
    float*    x      = (float*)p;            p += (size_t)SEQ * EMBED * 4;
    float*    qkvbuf = (float*)p;            p += (size_t)SEQ * QKVN * 4;
    ushort_t* hbf    = (ushort_t*)p;         p += (size_t)SEQ * EMBED * 2;
    ushort_t* hsbf   = (ushort_t*)p;         p += (size_t)SEQ * PATCH_KP * 2;
    ushort_t* wbuf   = (ushort_t*)p;
    ushort_t* fc1out = (ushort_t*)qkvbuf;
    ushort_t* qbv = wbuf;
    ushort_t* kbv = qbv + (size_t)HEADS * SEQ * 96;
    ushort_t* vtb = kbv + (size_t)HEADS * SEQ * 96;

    const dim3 tblk(32, 8);
    auto tgrid = [](int N, int Kp) { return dim3(N / 32, Kp / 32); };
    auto ggrid = [](int M, int N) { return dim3(N / 128, M / 128); };

    cast_hs<<<(SEQ * PATCH_KP + 255) / 256, 256, 0, stream>>>(hs, hsbf);
    transpose_cast<<<tgrid(EMBED, PATCH_KP), tblk, 0, stream>>>(
        patch_w, wbuf, PATCH_IN, EMBED, PATCH_KP);
    gemm_bf16<0, 0, 0><<<ggrid(SEQ, EMBED), 256, 0, stream>>>(
        hsbf, wbuf, nullptr, x, SEQ, EMBED, PATCH_KP);

    for (int i = 0; i < 2; ++i) {
        ln_f32<<<SEQ, 256, 0, stream>>>(x, ln1_w + i * EMBED, ln1_b + i * EMBED, hbf, EMBED);
        transpose_cast<<<tgrid(QKVN, EMBED), tblk, 0, stream>>>(
            qkv_w + (size_t)i * EMBED * QKVN, wbuf, EMBED, QKVN, EMBED);
        gemm_bf16<0, 0, 0><<<ggrid(SEQ, QKVN), 256, 0, stream>>>(
            hbf, wbuf, qkv_b + i * QKVN, qkvbuf, SEQ, QKVN, EMBED);
        rope_cast_qk<<<SEQ * HEADS * 48 / 256, 256, 0, stream>>>(qkvbuf, pos, qbv, kbv);
        v_transpose<<<HEADS * 80 * SEQ / 256, 256, 0, stream>>>(qkvbuf, vtb);
        attn_mfma<<<dim3(HEADS, NSEG, SEGLEN / 64), 256, 0, stream>>>(qbv, kbv, vtb, hbf);
        transpose_cast<<<tgrid(EMBED, EMBED), tblk, 0, stream>>>(
            proj_w + (size_t)i * EMBED * EMBED, wbuf, EMBED, EMBED, EMBED);
        gemm_bf16<0, 1, 0><<<ggrid(SEQ, EMBED), 256, 0, stream>>>(
            hbf, wbuf, proj_b + i * EMBED, x, SEQ, EMBED, EMBED);
        ln_f32<<<SEQ, 256, 0, stream>>>(x, ln2_w + i * EMBED, ln2_b + i * EMBED, hbf, EMBED);
        transpose_cast<<<tgrid(MLP, EMBED), tblk, 0, stream>>>(
            fc1_w + (size_t)i * EMBED * MLP, wbuf, EMBED, MLP, EMBED);
        gemm_bf16<1, 0, 1><<<ggrid(SEQ, MLP), 256, 0, stream>>>(
            hbf, wbuf, fc1_b + i * MLP, fc1out, SEQ, MLP, EMBED);
        transpose_cast<<<tgrid(EMBED, MLP), tblk, 0, stream>>>(
            fc2_w + (size_t)i * MLP * EMBED, wbuf, MLP, EMBED, MLP);
        gemm_bf16<0, 1, 0><<<ggrid(SEQ, EMBED), 256, 0, stream>>>(
            fc1out, wbuf, fc2_b + i * EMBED, x, SEQ, EMBED, MLP);
    }

    ln_f32<<<SEQ, 256, 0, stream>>>(x, mln_w, mln_b, hbf, EMBED);
    transpose_cast<<<tgrid(HIDDEN, 4 * EMBED), tblk, 0, stream>>>(
        w1, wbuf, 4 * EMBED, HIDDEN, 4 * EMBED);
    gemm_bf16<2, 0, 1><<<ggrid(MROWS, HIDDEN), 256, 0, stream>>>(
        hbf, wbuf, b1, fc1out, MROWS, HIDDEN, 4 * EMBED);
    transpose_cast<<<tgrid(HIDDEN, HIDDEN), tblk, 0, stream>>>(
        w2, wbuf, HIDDEN, HIDDEN, HIDDEN);
    gemm_bf16<0, 0, 0><<<ggrid(MROWS, HIDDEN), 256, 0, stream>>>(
        fc1out, wbuf, b2, out, MROWS, HIDDEN, HIDDEN);
}

// Round 7
// 814.973 us; speedup vs baseline: 13.7585x; 1.0294x over previous
//
#include <hip/hip_runtime.h>
#include <math.h>

#define SEQ    2048
#define EMBED  1280
#define HEADS  16
#define HD     80
#define MLP    5120
#define HIDDEN 3584
#define QKVN   3840
#define SEGLEN 1024
#define NSEG   2
#define PATCH_IN 1176
#define PATCH_KP 1280   // padded to mult of 128 (split-2 -> klen 640, nt=10)
#define MROWS  512

typedef __attribute__((ext_vector_type(8))) short bf16x8;
typedef __attribute__((ext_vector_type(4))) float f32x4;
typedef unsigned short ushort_t;

__device__ __forceinline__ ushort_t f2bf(float f) {
    unsigned u = __builtin_bit_cast(unsigned, f);
    unsigned r = u + 0x7FFFu + ((u >> 16) & 1u);   // RNE
    return (ushort_t)(r >> 16);
}

__device__ __forceinline__ void gld_lds16(const void* g, void* l) {
    __builtin_amdgcn_global_load_lds(
        (const __attribute__((address_space(1))) void*)g,
        (__attribute__((address_space(3))) void*)l, 16, 0, 0);
}

// ---------------------------------------------------------------------------
// bf16 MFMA GEMM, BK=64 double-buffered, counted-vmcnt pipeline (T4),
// T2 LDS XOR swizzle, T1 XCD swizzle. SPLIT-K (grid.z planes, K/SPLIT each,
// which MUST be a multiple of 64 — r6 bug: patch 1216/2=608 dropped 64 k!).
// SPLIT>1: f32 atomic partial sums (bias from z==0 plane only).
// ---------------------------------------------------------------------------
template<int EPI, int ACC, int OBF, int SPLIT>
__global__ __launch_bounds__(256) void gemm_bf16(
    const ushort_t* __restrict__ A, const ushort_t* __restrict__ Bt,
    const float* __restrict__ bias, void* __restrict__ Cout,
    int M, int N, int K)
{
    __shared__ __align__(16) short Abuf[2][128 * 64];
    __shared__ __align__(16) short Bbuf[2][128 * 64];

    const int tid  = threadIdx.x;
    const int lane = tid & 63, wid = tid >> 6;
    const int wr = wid >> 1, wc = wid & 1;

    // T1: XCD-aware bijective swizzle within each z-plane
    const int nwg  = gridDim.x * gridDim.y;
    const int flat = blockIdx.y * gridDim.x + blockIdx.x;
    int bx, by;
    if (nwg & 7) { bx = blockIdx.x; by = blockIdx.y; }
    else {
        const int swz = (flat & 7) * (nwg >> 3) + (flat >> 3);
        bx = swz % gridDim.x; by = swz / gridDim.x;
    }
    const int row0 = by * 128, col0 = bx * 128;
    const int kb = (SPLIT > 1) ? blockIdx.z * (K / SPLIT) : 0;
    const int klen = (SPLIT > 1) ? (K / SPLIT) : K;

    const int r0 = tid >> 3, s0 = tid & 7;      // staging row / 16B-slot
    const int lrow = lane & 15;
    const int lg = lane >> 4;
    const int rx = lrow & 7;                    // read-side swizzle key

    f32x4 acc[4][4] = {};

    auto stage = [&](int buf, int t) {
        const int k0 = kb + (t << 6);
        #pragma unroll
        for (int i = 0; i < 4; ++i) {
            const int r = r0 + i * 32;
            const int ksl = (s0 ^ (r & 7)) * 8;      // pre-swizzled source slot
            gld_lds16(A  + (size_t)(row0 + r) * K + k0 + ksl,
                      &Abuf[buf][(tid + i * 256) * 8]);
            gld_lds16(Bt + (size_t)(col0 + r) * K + k0 + ksl,
                      &Bbuf[buf][(tid + i * 256) * 8]);
        }
    };

    const int nt = klen >> 6;                    // klen always mult of 64, nt>=10
    stage(0, 0);
    stage(1, 1);                                 // 16 loads in flight

    int cur = 0;
    for (int t = 0; t < nt; ++t) {
        // wait ONLY for buf[cur]'s 8 loads; keep the next 8 in flight
        if (t < nt - 1) { asm volatile("s_waitcnt vmcnt(8)" ::: "memory"); }
        else            { asm volatile("s_waitcnt vmcnt(0)" ::: "memory"); }
        __builtin_amdgcn_s_barrier();            // all waves' cur-loads landed

        bf16x8 a[2][4], b[2][4];
        #pragma unroll
        for (int ko = 0; ko < 2; ++ko) {
            const int ts = ((ko * 4 + lg) ^ rx) * 8;    // swizzled read slot
            #pragma unroll
            for (int m = 0; m < 4; ++m)
                a[ko][m] = *(const bf16x8*)&Abuf[cur][(wr * 64 + m * 16 + lrow) * 64 + ts];
            #pragma unroll
            for (int n = 0; n < 4; ++n)
                b[ko][n] = *(const bf16x8*)&Bbuf[cur][(wc * 64 + n * 16 + lrow) * 64 + ts];
        }
        asm volatile("s_waitcnt lgkmcnt(0)" ::: "memory");   // frags in regs
        __builtin_amdgcn_s_barrier();            // all waves done READING cur
        __builtin_amdgcn_sched_barrier(0);       // pin stage below the barrier

        if (t + 2 < nt) stage(cur, t + 2);       // overwrite cur for t+2

        #pragma unroll
        for (int ko = 0; ko < 2; ++ko)
            #pragma unroll
            for (int m = 0; m < 4; ++m)
                #pragma unroll
                for (int n = 0; n < 4; ++n)
                    acc[m][n] = __builtin_amdgcn_mfma_f32_16x16x32_bf16(
                        a[ko][m], b[ko][n], acc[m][n], 0, 0, 0);
        cur ^= 1;
    }

    // epilogue: C/D layout col = lane&15, row = (lane>>4)*4 + reg
    const int rbase = lg * 4;
    #pragma unroll
    for (int n = 0; n < 4; ++n) {
        const int c = col0 + wc * 64 + n * 16 + lrow;
        const float bv = bias ? bias[c] : 0.f;
        #pragma unroll
        for (int m = 0; m < 4; ++m) {
            const int rb = row0 + wr * 64 + m * 16 + rbase;
            #pragma unroll
            for (int g = 0; g < 4; ++g) {
                const size_t idx = (size_t)(rb + g) * N + c;
                if (SPLIT > 1) {
                    // partial sum; bias contributed only by plane z==0
                    float v = acc[m][n][g] + (blockIdx.z == 0 ? bv : 0.f);
                    unsafeAtomicAdd(&((float*)Cout)[idx], v);
                } else {
                    float v = acc[m][n][g] + bv;
                    if (EPI == 1) v = v / (1.f + expf(-v));
                    if (EPI == 2) v = 0.5f * v * (1.f + erff(v * 0.70710678f));
                    if (OBF) {
                        ((ushort_t*)Cout)[idx] = f2bf(v);
                    } else {
                        float* Cf = (float*)Cout;
                        if (ACC) v += Cf[idx];
                        Cf[idx] = v;
                    }
                }
            }
        }
    }
}

// ---------------------------------------------------------------------------
// transpose + cast (unchanged)
// ---------------------------------------------------------------------------
__global__ __launch_bounds__(256) void transpose_cast(
    const float* __restrict__ in, ushort_t* __restrict__ out, int K, int N, int Kp)
{
    __shared__ float t[32][33];
    const int n0 = blockIdx.x * 32, k0 = blockIdx.y * 32;
    const int tx = threadIdx.x, ty = threadIdx.y;
    #pragma unroll
    for (int j = 0; j < 4; ++j) {
        int k = k0 + ty + j * 8;
        t[ty + j * 8][tx] = (k < K) ? in[(size_t)k * N + n0 + tx] : 0.f;
    }
    __syncthreads();
    #pragma unroll
    for (int j = 0; j < 4; ++j) {
        int n = n0 + ty + j * 8;
        out[(size_t)n * Kp + k0 + tx] = f2bf(t[tx][ty + j * 8]);
    }
}

__global__ __launch_bounds__(256) void cast_hs(
    const float* __restrict__ in, ushort_t* __restrict__ out)
{
    int idx = blockIdx.x * 256 + threadIdx.x;
    if (idx >= SEQ * PATCH_KP) return;
    int s = idx / PATCH_KP, k = idx % PATCH_KP;
    out[idx] = (k < PATCH_IN) ? f2bf(in[(size_t)s * PATCH_IN + k]) : 0;
}

// ---------------------------------------------------------------------------
// LayerNorm (unchanged)
// ---------------------------------------------------------------------------
__global__ __launch_bounds__(256) void ln_f32(
    const float* __restrict__ x, const float* __restrict__ w,
    const float* __restrict__ b, ushort_t* __restrict__ y, int D)
{
    const int row = blockIdx.x;
    const float* xr = x + (size_t)row * D;
    float s = 0.f, ss = 0.f;
    for (int d = threadIdx.x; d < D; d += 256) {
        float v = xr[d];
        s += v; ss = fmaf(v, v, ss);
    }
    __shared__ float red[2][4];
    const int lane = threadIdx.x & 63, wid = threadIdx.x >> 6;
    #pragma unroll
    for (int off = 32; off; off >>= 1) {
        s  += __shfl_xor(s,  off);
        ss += __shfl_xor(ss, off);
    }
    if (lane == 0) { red[0][wid] = s; red[1][wid] = ss; }
    __syncthreads();
    s  = red[0][0] + red[0][1] + red[0][2] + red[0][3];
    ss = red[1][0] + red[1][1] + red[1][2] + red[1][3];
    const float mu  = s / D;
    const float var = ss / D - mu * mu;
    const float inv = rsqrtf(var + 1e-6f);
    ushort_t* yr = y + (size_t)row * D;
    for (int d = threadIdx.x; d < D; d += 256)
        yr[d] = f2bf((xr[d] - mu) * inv * w[d] + b[d]);
}

// ---------------------------------------------------------------------------
// RoPE + scale + bf16 cast + head-major relayout (unchanged)
// ---------------------------------------------------------------------------
__global__ __launch_bounds__(256) void rope_cast_qk(
    const float* __restrict__ qkv, const int* __restrict__ pos,
    ushort_t* __restrict__ qb, ushort_t* __restrict__ kb)
{
    int idx = blockIdx.x * 256 + threadIdx.x;
    const int j = idx % 48;
    const int h = (idx / 48) % HEADS;
    const int s = idx / (48 * HEADS);
    if (s >= SEQ) return;
    const size_t ob = ((size_t)h * SEQ + s) * 96;
    if (j >= 40) {
        qb[ob + 40 + j] = 0; qb[ob + 48 + j] = 0;
        kb[ob + 40 + j] = 0; kb[ob + 48 + j] = 0;
        return;
    }
    const float p = (float)pos[s * 2 + (j / 20)];
    const float f = p * powf(10000.f, -(float)(j % 20) / 20.f);
    float c, sn;
    sincosf(f, &c, &sn);
    const float* q = qkv + (size_t)s * QKVN + h * HD;
    const float* k = q + EMBED;
    const float scale = 0.11180339887498949f;
    float q1 = q[j], q2 = q[j + 40];
    qb[ob + j]      = f2bf((q1 * c - q2 * sn) * scale);
    qb[ob + j + 40] = f2bf((q2 * c + q1 * sn) * scale);
    float k1 = k[j], k2 = k[j + 40];
    kb[ob + j]      = f2bf(k1 * c - k2 * sn);
    kb[ob + j + 40] = f2bf(k2 * c + k1 * sn);
}

__global__ __launch_bounds__(256) void v_transpose(
    const float* __restrict__ qkv, ushort_t* __restrict__ vtb)
{
    int idx = blockIdx.x * 256 + threadIdx.x;
    int s = idx & (SEQ - 1);
    int d = (idx >> 11) % 80;
    int h = idx / (SEQ * 80);
    if (h >= HEADS) return;
    vtb[((size_t)h * 80 + d) * SEQ + s] =
        f2bf(qkv[(size_t)s * QKVN + 2 * EMBED + h * HD + d]);
}

// ---------------------------------------------------------------------------
// MFMA flash attention (unchanged)
// ---------------------------------------------------------------------------
#define AKC  64
#define KSTR 104
#define VSTR 72
#define PSTR 72

__global__ __launch_bounds__(256) void attn_mfma(
    const ushort_t* __restrict__ qb, const ushort_t* __restrict__ kb,
    const ushort_t* __restrict__ vtb, ushort_t* __restrict__ out)
{
    const int hh = blockIdx.x;
    const int seg = blockIdx.y;
    const int tid = threadIdx.x, lane = tid & 63, wid = tid >> 6;
    const int lr = lane & 15, lg = lane >> 4;

    __shared__ __align__(16) short Ks[AKC * KSTR];
    __shared__ __align__(16) short Vs[80 * VSTR];
    __shared__ __align__(16) short Ps[4][16 * PSTR];

    const int sq = seg * SEGLEN;
    const int qrow0 = sq + blockIdx.z * 64 + wid * 16;

    bf16x8 qf[3];
    #pragma unroll
    for (int f = 0; f < 3; ++f)
        qf[f] = *(const bf16x8*)&qb[((size_t)hh * SEQ + qrow0 + lr) * 96 + f * 32 + lg * 8];

    f32x4 o[5] = {};
    float m[4], l[4];
    #pragma unroll
    for (int g = 0; g < 4; ++g) { m[g] = -1e30f; l[g] = 0.f; }

    for (int c0 = 0; c0 < SEGLEN; c0 += AKC) {
        __syncthreads();
        #pragma unroll
        for (int i = 0; i < 3; ++i) {
            int id = tid + i * 256;
            int r = id / 12, s = id % 12;
            *(bf16x8*)&Ks[r * KSTR + s * 8] =
                *(const bf16x8*)&kb[((size_t)hh * SEQ + sq + c0 + r) * 96 + s * 8];
        }
        #pragma unroll
        for (int i = 0; i < 3; ++i) {
            int id = tid + i * 256;
            if (id < 640) {
                int d = id / 8, s = id % 8;
                *(bf16x8*)&Vs[d * VSTR + s * 8] =
                    *(const bf16x8*)&vtb[((size_t)hh * 80 + d) * SEQ + sq + c0 + s * 8];
            }
        }
        __syncthreads();

        f32x4 sc[4] = {};
        #pragma unroll
        for (int kt = 0; kt < 4; ++kt)
            #pragma unroll
            for (int f = 0; f < 3; ++f) {
                bf16x8 kf = *(const bf16x8*)&Ks[(kt * 16 + lr) * KSTR + f * 32 + lg * 8];
                sc[kt] = __builtin_amdgcn_mfma_f32_16x16x32_bf16(qf[f], kf, sc[kt], 0, 0, 0);
            }

        float corr[4], ps[4];
        #pragma unroll
        for (int g = 0; g < 4; ++g) {
            float v = fmaxf(fmaxf(sc[0][g], sc[1][g]), fmaxf(sc[2][g], sc[3][g]));
            v = fmaxf(v, __shfl_xor(v, 1));
            v = fmaxf(v, __shfl_xor(v, 2));
            v = fmaxf(v, __shfl_xor(v, 4));
            v = fmaxf(v, __shfl_xor(v, 8));
            const float mn = fmaxf(m[g], v);
            corr[g] = __expf(m[g] - mn);
            m[g] = mn;
            ps[g] = 0.f;
        }
        #pragma unroll
        for (int kt = 0; kt < 4; ++kt)
            #pragma unroll
            for (int g = 0; g < 4; ++g) {
                float p = __expf(sc[kt][g] - m[g]);
                ps[g] += p;
                Ps[wid][(lg * 4 + g) * PSTR + kt * 16 + lr] = f2bf(p);
            }
        #pragma unroll
        for (int g = 0; g < 4; ++g) {
            float rs = ps[g];
            rs += __shfl_xor(rs, 1);
            rs += __shfl_xor(rs, 2);
            rs += __shfl_xor(rs, 4);
            rs += __shfl_xor(rs, 8);
            l[g] = l[g] * corr[g] + rs;
        }
        #pragma unroll
        for (int n = 0; n < 5; ++n)
            #pragma unroll
            for (int g = 0; g < 4; ++g) o[n][g] *= corr[g];

        #pragma unroll
        for (int jf = 0; jf < 2; ++jf) {
            bf16x8 pa = *(const bf16x8*)&Ps[wid][lr * PSTR + jf * 32 + lg * 8];
            #pragma unroll
            for (int n = 0; n < 5; ++n) {
                bf16x8 vf = *(const bf16x8*)&Vs[(n * 16 + lr) * VSTR + jf * 32 + lg * 8];
                o[n] = __builtin_amdgcn_mfma_f32_16x16x32_bf16(pa, vf, o[n], 0, 0, 0);
            }
        }
    }

    #pragma unroll
    for (int g = 0; g < 4; ++g) {
        const float inv = 1.f / l[g];
        const int r = qrow0 + lg * 4 + g;
        #pragma unroll
        for (int n = 0; n < 5; ++n)
            out[(size_t)r * EMBED + hh * HD + n * 16 + lr] = f2bf(o[n][g] * inv);
    }
}

// ---------------------------------------------------------------------------

extern "C" void kernel_launch(void* const* d_in, const int* in_sizes, int n_in,
                              void* d_out, int out_size, void* d_ws, size_t ws_size,
                              hipStream_t stream)
{
    const float* hs      = (const float*)d_in[0];
    const int*   pos     = (const int*)  d_in[1];
    const float* patch_w = (const float*)d_in[3];
    const float* ln1_w   = (const float*)d_in[4];
    const float* ln1_b   = (const float*)d_in[5];
    const float* ln2_w   = (const float*)d_in[6];
    const float* ln2_b   = (const float*)d_in[7];
    const float* qkv_w   = (const float*)d_in[8];
    const float* qkv_b   = (const float*)d_in[9];
    const float* proj_w  = (const float*)d_in[10];
    const float* proj_b  = (const float*)d_in[11];
    const float* fc1_w   = (const float*)d_in[12];
    const float* fc1_b   = (const float*)d_in[13];
    const float* fc2_w   = (const float*)d_in[14];
    const float* fc2_b   = (const float*)d_in[15];
    const float* mln_w   = (const float*)d_in[16];
    const float* mln_b   = (const float*)d_in[17];
    const float* w1      = (const float*)d_in[18];
    const float* b1      = (const float*)d_in[19];
    const float* w2      = (const float*)d_in[20];
    const float* b2      = (const float*)d_in[21];
    float* out = (float*)d_out;

    char* p = (char*)d_ws;
    float*    x      = (float*)p;            p += (size_t)SEQ * EMBED * 4;
    float*    qkvbuf = (float*)p;            p += (size_t)SEQ * QKVN * 4;
    ushort_t* hbf    = (ushort_t*)p;         p += (size_t)SEQ * EMBED * 2;
    ushort_t* hsbf   = (ushort_t*)p;         p += (size_t)SEQ * PATCH_KP * 2;
    ushort_t* wbuf   = (ushort_t*)p;
    ushort_t* fc1out = (ushort_t*)qkvbuf;
    ushort_t* qbv = wbuf;
    ushort_t* kbv = qbv + (size_t)HEADS * SEQ * 96;
    ushort_t* vtb = kbv + (size_t)HEADS * SEQ * 96;

    const dim3 tblk(32, 8);
    auto tgrid = [](int N, int Kp) { return dim3(N / 32, Kp / 32); };
    auto ggrid = [](int M, int N, int S = 1) { return dim3(N / 128, M / 128, S); };

    cast_hs<<<(SEQ * PATCH_KP + 255) / 256, 256, 0, stream>>>(hs, hsbf);
    transpose_cast<<<tgrid(EMBED, PATCH_KP), tblk, 0, stream>>>(
        patch_w, wbuf, PATCH_IN, EMBED, PATCH_KP);
    // patch embed via split-K atomics: zero x first
    hipMemsetAsync(x, 0, (size_t)SEQ * EMBED * 4, stream);
    gemm_bf16<0, 0, 0, 2><<<ggrid(SEQ, EMBED, 2), 256, 0, stream>>>(
        hsbf, wbuf, nullptr, x, SEQ, EMBED, PATCH_KP);

    for (int i = 0; i < 2; ++i) {
        ln_f32<<<SEQ, 256, 0, stream>>>(x, ln1_w + i * EMBED, ln1_b + i * EMBED, hbf, EMBED);
        transpose_cast<<<tgrid(QKVN, EMBED), tblk, 0, stream>>>(
            qkv_w + (size_t)i * EMBED * QKVN, wbuf, EMBED, QKVN, EMBED);
        gemm_bf16<0, 0, 0, 1><<<ggrid(SEQ, QKVN), 256, 0, stream>>>(
            hbf, wbuf, qkv_b + i * QKVN, qkvbuf, SEQ, QKVN, EMBED);
        rope_cast_qk<<<SEQ * HEADS * 48 / 256, 256, 0, stream>>>(qkvbuf, pos, qbv, kbv);
        v_transpose<<<HEADS * 80 * SEQ / 256, 256, 0, stream>>>(qkvbuf, vtb);
        attn_mfma<<<dim3(HEADS, NSEG, SEGLEN / 64), 256, 0, stream>>>(qbv, kbv, vtb, hbf);
        transpose_cast<<<tgrid(EMBED, EMBED), tblk, 0, stream>>>(
            proj_w + (size_t)i * EMBED * EMBED, wbuf, EMBED, EMBED, EMBED);
        gemm_bf16<0, 1, 0, 2><<<ggrid(SEQ, EMBED, 2), 256, 0, stream>>>(
            hbf, wbuf, proj_b + i * EMBED, x, SEQ, EMBED, EMBED);
        ln_f32<<<SEQ, 256, 0, stream>>>(x, ln2_w + i * EMBED, ln2_b + i * EMBED, hbf, EMBED);
        transpose_cast<<<tgrid(MLP, EMBED), tblk, 0, stream>>>(
            fc1_w + (size_t)i * EMBED * MLP, wbuf, EMBED, MLP, EMBED);
        gemm_bf16<1, 0, 1, 1><<<ggrid(SEQ, MLP), 256, 0, stream>>>(
            hbf, wbuf, fc1_b + i * MLP, fc1out, SEQ, MLP, EMBED);
        transpose_cast<<<tgrid(EMBED, MLP), tblk, 0, stream>>>(
            fc2_w + (size_t)i * MLP * EMBED, wbuf, MLP, EMBED, MLP);
        gemm_bf16<0, 1, 0, 4><<<ggrid(SEQ, EMBED, 4), 256, 0, stream>>>(
            fc1out, wbuf, fc2_b + i * EMBED, x, SEQ, EMBED, MLP);
    }

    ln_f32<<<SEQ, 256, 0, stream>>>(x, mln_w, mln_b, hbf, EMBED);
    transpose_cast<<<tgrid(HIDDEN, 4 * EMBED), tblk, 0, stream>>>(
        w1, wbuf, 4 * EMBED, HIDDEN, 4 * EMBED);
    gemm_bf16<2, 0, 1, 1><<<ggrid(MROWS, HIDDEN), 256, 0, stream>>>(
        hbf, wbuf, b1, fc1out, MROWS, HIDDEN, 4 * EMBED);
    transpose_cast<<<tgrid(HIDDEN, HIDDEN), tblk, 0, stream>>>(
        w2, wbuf, HIDDEN, HIDDEN, HIDDEN);
    // mrg2 via split-K atomics: zero out first
    hipMemsetAsync(out, 0, (size_t)MROWS * HIDDEN * 4, stream);
    gemm_bf16<0, 0, 0, 4><<<ggrid(MROWS, HIDDEN, 4), 256, 0, stream>>>(
        fc1out, wbuf, b2, out, MROWS, HIDDEN, HIDDEN);
}

// Round 8
// 785.477 us; speedup vs baseline: 14.2752x; 1.0376x over previous
//
#include <hip/hip_runtime.h>
#include <math.h>

#define SEQ    2048
#define EMBED  1280
#define HEADS  16
#define HD     80
#define MLP    5120
#define HIDDEN 3584
#define QKVN   3840
#define SEGLEN 1024
#define NSEG   2
#define PATCH_IN 1176
#define PATCH_KP 1280   // padded to mult of 128 (split-2 -> klen 640, nt=10)
#define MROWS  512

typedef __attribute__((ext_vector_type(8))) short bf16x8;
typedef __attribute__((ext_vector_type(4))) short s16x4;
typedef __attribute__((ext_vector_type(4))) float f32x4;
typedef unsigned short ushort_t;

__device__ __forceinline__ ushort_t f2bf(float f) {
    unsigned u = __builtin_bit_cast(unsigned, f);
    unsigned r = u + 0x7FFFu + ((u >> 16) & 1u);   // RNE
    return (ushort_t)(r >> 16);
}

__device__ __forceinline__ void gld_lds16(const void* g, void* l) {
    __builtin_amdgcn_global_load_lds(
        (const __attribute__((address_space(1))) void*)g,
        (__attribute__((address_space(3))) void*)l, 16, 0, 0);
}

// ---------------------------------------------------------------------------
// bf16 MFMA GEMM, BK=64 double-buffered, counted-vmcnt pipeline (T4),
// T2 LDS XOR swizzle, T1 XCD swizzle. SPLIT-K (grid.z planes, K/SPLIT each,
// which MUST be a multiple of 64). SPLIT>1: f32 atomic partial sums
// (bias from z==0 plane only; EPI ignored -> apply nonlinearity in a
// separate pass).
// ---------------------------------------------------------------------------
template<int EPI, int ACC, int OBF, int SPLIT>
__global__ __launch_bounds__(256) void gemm_bf16(
    const ushort_t* __restrict__ A, const ushort_t* __restrict__ Bt,
    const float* __restrict__ bias, void* __restrict__ Cout,
    int M, int N, int K)
{
    __shared__ __align__(16) short Abuf[2][128 * 64];
    __shared__ __align__(16) short Bbuf[2][128 * 64];

    const int tid  = threadIdx.x;
    const int lane = tid & 63, wid = tid >> 6;
    const int wr = wid >> 1, wc = wid & 1;

    // T1: XCD-aware bijective swizzle within each z-plane
    const int nwg  = gridDim.x * gridDim.y;
    const int flat = blockIdx.y * gridDim.x + blockIdx.x;
    int bx, by;
    if (nwg & 7) { bx = blockIdx.x; by = blockIdx.y; }
    else {
        const int swz = (flat & 7) * (nwg >> 3) + (flat >> 3);
        bx = swz % gridDim.x; by = swz / gridDim.x;
    }
    const int row0 = by * 128, col0 = bx * 128;
    const int kb = (SPLIT > 1) ? blockIdx.z * (K / SPLIT) : 0;
    const int klen = (SPLIT > 1) ? (K / SPLIT) : K;

    const int r0 = tid >> 3, s0 = tid & 7;      // staging row / 16B-slot
    const int lrow = lane & 15;
    const int lg = lane >> 4;
    const int rx = lrow & 7;                    // read-side swizzle key

    f32x4 acc[4][4] = {};

    auto stage = [&](int buf, int t) {
        const int k0 = kb + (t << 6);
        #pragma unroll
        for (int i = 0; i < 4; ++i) {
            const int r = r0 + i * 32;
            const int ksl = (s0 ^ (r & 7)) * 8;      // pre-swizzled source slot
            gld_lds16(A  + (size_t)(row0 + r) * K + k0 + ksl,
                      &Abuf[buf][(tid + i * 256) * 8]);
            gld_lds16(Bt + (size_t)(col0 + r) * K + k0 + ksl,
                      &Bbuf[buf][(tid + i * 256) * 8]);
        }
    };

    const int nt = klen >> 6;                    // klen always mult of 64
    stage(0, 0);
    stage(1, 1);                                 // 16 loads in flight

    int cur = 0;
    for (int t = 0; t < nt; ++t) {
        // wait ONLY for buf[cur]'s 8 loads; keep the next 8 in flight
        if (t < nt - 1) { asm volatile("s_waitcnt vmcnt(8)" ::: "memory"); }
        else            { asm volatile("s_waitcnt vmcnt(0)" ::: "memory"); }
        __builtin_amdgcn_s_barrier();            // all waves' cur-loads landed

        bf16x8 a[2][4], b[2][4];
        #pragma unroll
        for (int ko = 0; ko < 2; ++ko) {
            const int ts = ((ko * 4 + lg) ^ rx) * 8;    // swizzled read slot
            #pragma unroll
            for (int m = 0; m < 4; ++m)
                a[ko][m] = *(const bf16x8*)&Abuf[cur][(wr * 64 + m * 16 + lrow) * 64 + ts];
            #pragma unroll
            for (int n = 0; n < 4; ++n)
                b[ko][n] = *(const bf16x8*)&Bbuf[cur][(wc * 64 + n * 16 + lrow) * 64 + ts];
        }
        asm volatile("s_waitcnt lgkmcnt(0)" ::: "memory");   // frags in regs
        __builtin_amdgcn_s_barrier();            // all waves done READING cur
        __builtin_amdgcn_sched_barrier(0);       // pin stage below the barrier

        if (t + 2 < nt) stage(cur, t + 2);       // overwrite cur for t+2

        #pragma unroll
        for (int ko = 0; ko < 2; ++ko)
            #pragma unroll
            for (int m = 0; m < 4; ++m)
                #pragma unroll
                for (int n = 0; n < 4; ++n)
                    acc[m][n] = __builtin_amdgcn_mfma_f32_16x16x32_bf16(
                        a[ko][m], b[ko][n], acc[m][n], 0, 0, 0);
        cur ^= 1;
    }

    // epilogue: C/D layout col = lane&15, row = (lane>>4)*4 + reg
    const int rbase = lg * 4;
    #pragma unroll
    for (int n = 0; n < 4; ++n) {
        const int c = col0 + wc * 64 + n * 16 + lrow;
        const float bv = bias ? bias[c] : 0.f;
        #pragma unroll
        for (int m = 0; m < 4; ++m) {
            const int rb = row0 + wr * 64 + m * 16 + rbase;
            #pragma unroll
            for (int g = 0; g < 4; ++g) {
                const size_t idx = (size_t)(rb + g) * N + c;
                if (SPLIT > 1) {
                    // partial sum; bias contributed only by plane z==0
                    float v = acc[m][n][g] + (blockIdx.z == 0 ? bv : 0.f);
                    unsafeAtomicAdd(&((float*)Cout)[idx], v);
                } else {
                    float v = acc[m][n][g] + bv;
                    if (EPI == 1) v = v / (1.f + expf(-v));
                    if (EPI == 2) v = 0.5f * v * (1.f + erff(v * 0.70710678f));
                    if (OBF) {
                        ((ushort_t*)Cout)[idx] = f2bf(v);
                    } else {
                        float* Cf = (float*)Cout;
                        if (ACC) v += Cf[idx];
                        Cf[idx] = v;
                    }
                }
            }
        }
    }
}

// ---------------------------------------------------------------------------
// transpose + f32->bf16 cast: in (K,N) f32 -> out (N,Kp) bf16, zero-pad.
// r8: phase-2 writes 16B per thread (was 2B scalar — 128B/wave, G13 hit).
// 128 threads each pack 8 k-consecutive bf16 from the LDS tile.
// ---------------------------------------------------------------------------
__global__ __launch_bounds__(256) void transpose_cast(
    const float* __restrict__ in, ushort_t* __restrict__ out, int K, int N, int Kp)
{
    __shared__ float t[32][33];
    const int n0 = blockIdx.x * 32, k0 = blockIdx.y * 32;
    const int tx = threadIdx.x, ty = threadIdx.y;   // 32 x 8
    #pragma unroll
    for (int j = 0; j < 4; ++j) {
        int k = k0 + ty + j * 8;
        t[ty + j * 8][tx] = (k < K) ? in[(size_t)k * N + n0 + tx] : 0.f;
    }
    __syncthreads();
    const int tid = ty * 32 + tx;
    if (tid < 128) {
        const int n = tid >> 2, kg = (tid & 3) * 8;
        bf16x8 v;
        #pragma unroll
        for (int j = 0; j < 8; ++j)
            v[j] = (short)f2bf(t[kg + j][n]);        // 2-way LDS aliasing: free
        *(bf16x8*)&out[(size_t)(n0 + n) * Kp + k0 + kg] = v;   // 16B store
    }
}

__global__ __launch_bounds__(256) void cast_hs(
    const float* __restrict__ in, ushort_t* __restrict__ out)
{
    int idx = blockIdx.x * 256 + threadIdx.x;
    if (idx >= SEQ * PATCH_KP) return;
    int s = idx / PATCH_KP, k = idx % PATCH_KP;
    out[idx] = (k < PATCH_IN) ? f2bf(in[(size_t)s * PATCH_IN + k]) : 0;
}

// gelu epilogue for split-K mrg1: bf16(gelu(f32 partial-sum))
__global__ __launch_bounds__(256) void gelu_cast(
    const float* __restrict__ in, ushort_t* __restrict__ out)
{
    const int idx = blockIdx.x * 256 + threadIdx.x;   // 4 elems each
    f32x4 v = ((const f32x4*)in)[idx];
    s16x4 r;
    #pragma unroll
    for (int j = 0; j < 4; ++j)
        r[j] = (short)f2bf(0.5f * v[j] * (1.f + erff(v[j] * 0.70710678f)));
    *(s16x4*)&out[idx * 4] = r;
}

// ---------------------------------------------------------------------------
// LayerNorm (unchanged)
// ---------------------------------------------------------------------------
__global__ __launch_bounds__(256) void ln_f32(
    const float* __restrict__ x, const float* __restrict__ w,
    const float* __restrict__ b, ushort_t* __restrict__ y, int D)
{
    const int row = blockIdx.x;
    const float* xr = x + (size_t)row * D;
    float s = 0.f, ss = 0.f;
    for (int d = threadIdx.x; d < D; d += 256) {
        float v = xr[d];
        s += v; ss = fmaf(v, v, ss);
    }
    __shared__ float red[2][4];
    const int lane = threadIdx.x & 63, wid = threadIdx.x >> 6;
    #pragma unroll
    for (int off = 32; off; off >>= 1) {
        s  += __shfl_xor(s,  off);
        ss += __shfl_xor(ss, off);
    }
    if (lane == 0) { red[0][wid] = s; red[1][wid] = ss; }
    __syncthreads();
    s  = red[0][0] + red[0][1] + red[0][2] + red[0][3];
    ss = red[1][0] + red[1][1] + red[1][2] + red[1][3];
    const float mu  = s / D;
    const float var = ss / D - mu * mu;
    const float inv = rsqrtf(var + 1e-6f);
    ushort_t* yr = y + (size_t)row * D;
    for (int d = threadIdx.x; d < D; d += 256)
        yr[d] = f2bf((xr[d] - mu) * inv * w[d] + b[d]);
}

// ---------------------------------------------------------------------------
// RoPE + scale + bf16 cast + head-major relayout (unchanged)
// ---------------------------------------------------------------------------
__global__ __launch_bounds__(256) void rope_cast_qk(
    const float* __restrict__ qkv, const int* __restrict__ pos,
    ushort_t* __restrict__ qb, ushort_t* __restrict__ kb)
{
    int idx = blockIdx.x * 256 + threadIdx.x;
    const int j = idx % 48;
    const int h = (idx / 48) % HEADS;
    const int s = idx / (48 * HEADS);
    if (s >= SEQ) return;
    const size_t ob = ((size_t)h * SEQ + s) * 96;
    if (j >= 40) {
        qb[ob + 40 + j] = 0; qb[ob + 48 + j] = 0;
        kb[ob + 40 + j] = 0; kb[ob + 48 + j] = 0;
        return;
    }
    const float p = (float)pos[s * 2 + (j / 20)];
    const float f = p * powf(10000.f, -(float)(j % 20) / 20.f);
    float c, sn;
    sincosf(f, &c, &sn);
    const float* q = qkv + (size_t)s * QKVN + h * HD;
    const float* k = q + EMBED;
    const float scale = 0.11180339887498949f;
    float q1 = q[j], q2 = q[j + 40];
    qb[ob + j]      = f2bf((q1 * c - q2 * sn) * scale);
    qb[ob + j + 40] = f2bf((q2 * c + q1 * sn) * scale);
    float k1 = k[j], k2 = k[j + 40];
    kb[ob + j]      = f2bf(k1 * c - k2 * sn);
    kb[ob + j + 40] = f2bf(k2 * c + k1 * sn);
}

__global__ __launch_bounds__(256) void v_transpose(
    const float* __restrict__ qkv, ushort_t* __restrict__ vtb)
{
    int idx = blockIdx.x * 256 + threadIdx.x;
    int s = idx & (SEQ - 1);
    int d = (idx >> 11) % 80;
    int h = idx / (SEQ * 80);
    if (h >= HEADS) return;
    vtb[((size_t)h * 80 + d) * SEQ + s] =
        f2bf(qkv[(size_t)s * QKVN + 2 * EMBED + h * HD + d]);
}

// ---------------------------------------------------------------------------
// MFMA flash attention (unchanged)
// ---------------------------------------------------------------------------
#define AKC  64
#define KSTR 104
#define VSTR 72
#define PSTR 72

__global__ __launch_bounds__(256) void attn_mfma(
    const ushort_t* __restrict__ qb, const ushort_t* __restrict__ kb,
    const ushort_t* __restrict__ vtb, ushort_t* __restrict__ out)
{
    const int hh = blockIdx.x;
    const int seg = blockIdx.y;
    const int tid = threadIdx.x, lane = tid & 63, wid = tid >> 6;
    const int lr = lane & 15, lg = lane >> 4;

    __shared__ __align__(16) short Ks[AKC * KSTR];
    __shared__ __align__(16) short Vs[80 * VSTR];
    __shared__ __align__(16) short Ps[4][16 * PSTR];

    const int sq = seg * SEGLEN;
    const int qrow0 = sq + blockIdx.z * 64 + wid * 16;

    bf16x8 qf[3];
    #pragma unroll
    for (int f = 0; f < 3; ++f)
        qf[f] = *(const bf16x8*)&qb[((size_t)hh * SEQ + qrow0 + lr) * 96 + f * 32 + lg * 8];

    f32x4 o[5] = {};
    float m[4], l[4];
    #pragma unroll
    for (int g = 0; g < 4; ++g) { m[g] = -1e30f; l[g] = 0.f; }

    for (int c0 = 0; c0 < SEGLEN; c0 += AKC) {
        __syncthreads();
        #pragma unroll
        for (int i = 0; i < 3; ++i) {
            int id = tid + i * 256;
            int r = id / 12, s = id % 12;
            *(bf16x8*)&Ks[r * KSTR + s * 8] =
                *(const bf16x8*)&kb[((size_t)hh * SEQ + sq + c0 + r) * 96 + s * 8];
        }
        #pragma unroll
        for (int i = 0; i < 3; ++i) {
            int id = tid + i * 256;
            if (id < 640) {
                int d = id / 8, s = id % 8;
                *(bf16x8*)&Vs[d * VSTR + s * 8] =
                    *(const bf16x8*)&vtb[((size_t)hh * 80 + d) * SEQ + sq + c0 + s * 8];
            }
        }
        __syncthreads();

        f32x4 sc[4] = {};
        #pragma unroll
        for (int kt = 0; kt < 4; ++kt)
            #pragma unroll
            for (int f = 0; f < 3; ++f) {
                bf16x8 kf = *(const bf16x8*)&Ks[(kt * 16 + lr) * KSTR + f * 32 + lg * 8];
                sc[kt] = __builtin_amdgcn_mfma_f32_16x16x32_bf16(qf[f], kf, sc[kt], 0, 0, 0);
            }

        float corr[4], ps[4];
        #pragma unroll
        for (int g = 0; g < 4; ++g) {
            float v = fmaxf(fmaxf(sc[0][g], sc[1][g]), fmaxf(sc[2][g], sc[3][g]));
            v = fmaxf(v, __shfl_xor(v, 1));
            v = fmaxf(v, __shfl_xor(v, 2));
            v = fmaxf(v, __shfl_xor(v, 4));
            v = fmaxf(v, __shfl_xor(v, 8));
            const float mn = fmaxf(m[g], v);
            corr[g] = __expf(m[g] - mn);
            m[g] = mn;
            ps[g] = 0.f;
        }
        #pragma unroll
        for (int kt = 0; kt < 4; ++kt)
            #pragma unroll
            for (int g = 0; g < 4; ++g) {
                float p = __expf(sc[kt][g] - m[g]);
                ps[g] += p;
                Ps[wid][(lg * 4 + g) * PSTR + kt * 16 + lr] = f2bf(p);
            }
        #pragma unroll
        for (int g = 0; g < 4; ++g) {
            float rs = ps[g];
            rs += __shfl_xor(rs, 1);
            rs += __shfl_xor(rs, 2);
            rs += __shfl_xor(rs, 4);
            rs += __shfl_xor(rs, 8);
            l[g] = l[g] * corr[g] + rs;
        }
        #pragma unroll
        for (int n = 0; n < 5; ++n)
            #pragma unroll
            for (int g = 0; g < 4; ++g) o[n][g] *= corr[g];

        #pragma unroll
        for (int jf = 0; jf < 2; ++jf) {
            bf16x8 pa = *(const bf16x8*)&Ps[wid][lr * PSTR + jf * 32 + lg * 8];
            #pragma unroll
            for (int n = 0; n < 5; ++n) {
                bf16x8 vf = *(const bf16x8*)&Vs[(n * 16 + lr) * VSTR + jf * 32 + lg * 8];
                o[n] = __builtin_amdgcn_mfma_f32_16x16x32_bf16(pa, vf, o[n], 0, 0, 0);
            }
        }
    }

    #pragma unroll
    for (int g = 0; g < 4; ++g) {
        const float inv = 1.f / l[g];
        const int r = qrow0 + lg * 4 + g;
        #pragma unroll
        for (int n = 0; n < 5; ++n)
            out[(size_t)r * EMBED + hh * HD + n * 16 + lr] = f2bf(o[n][g] * inv);
    }
}

// ---------------------------------------------------------------------------

extern "C" void kernel_launch(void* const* d_in, const int* in_sizes, int n_in,
                              void* d_out, int out_size, void* d_ws, size_t ws_size,
                              hipStream_t stream)
{
    const float* hs      = (const float*)d_in[0];
    const int*   pos     = (const int*)  d_in[1];
    const float* patch_w = (const float*)d_in[3];
    const float* ln1_w   = (const float*)d_in[4];
    const float* ln1_b   = (const float*)d_in[5];
    const float* ln2_w   = (const float*)d_in[6];
    const float* ln2_b   = (const float*)d_in[7];
    const float* qkv_w   = (const float*)d_in[8];
    const float* qkv_b   = (const float*)d_in[9];
    const float* proj_w  = (const float*)d_in[10];
    const float* proj_b  = (const float*)d_in[11];
    const float* fc1_w   = (const float*)d_in[12];
    const float* fc1_b   = (const float*)d_in[13];
    const float* fc2_w   = (const float*)d_in[14];
    const float* fc2_b   = (const float*)d_in[15];
    const float* mln_w   = (const float*)d_in[16];
    const float* mln_b   = (const float*)d_in[17];
    const float* w1      = (const float*)d_in[18];
    const float* b1      = (const float*)d_in[19];
    const float* w2      = (const float*)d_in[20];
    const float* b2      = (const float*)d_in[21];
    float* out = (float*)d_out;

    char* p = (char*)d_ws;
    float*    x      = (float*)p;            p += (size_t)SEQ * EMBED * 4;
    float*    qkvbuf = (float*)p;            p += (size_t)SEQ * QKVN * 4;
    ushort_t* hbf    = (ushort_t*)p;         p += (size_t)SEQ * EMBED * 2;
    ushort_t* hsbf   = (ushort_t*)p;         p += (size_t)SEQ * PATCH_KP * 2;
    ushort_t* wbuf   = (ushort_t*)p;
    ushort_t* fc1out = (ushort_t*)qkvbuf;                      // bf16 outputs
    float*    mrg1f  = (float*)((char*)qkvbuf + (8 << 20));    // f32 partials (7.3 MB)
    ushort_t* qbv = wbuf;
    ushort_t* kbv = qbv + (size_t)HEADS * SEQ * 96;
    ushort_t* vtb = kbv + (size_t)HEADS * SEQ * 96;

    const dim3 tblk(32, 8);
    auto tgrid = [](int N, int Kp) { return dim3(N / 32, Kp / 32); };
    auto ggrid = [](int M, int N, int S = 1) { return dim3(N / 128, M / 128, S); };

    cast_hs<<<(SEQ * PATCH_KP + 255) / 256, 256, 0, stream>>>(hs, hsbf);
    transpose_cast<<<tgrid(EMBED, PATCH_KP), tblk, 0, stream>>>(
        patch_w, wbuf, PATCH_IN, EMBED, PATCH_KP);
    // patch embed via split-K atomics: zero x first
    hipMemsetAsync(x, 0, (size_t)SEQ * EMBED * 4, stream);
    gemm_bf16<0, 0, 0, 2><<<ggrid(SEQ, EMBED, 2), 256, 0, stream>>>(
        hsbf, wbuf, nullptr, x, SEQ, EMBED, PATCH_KP);

    for (int i = 0; i < 2; ++i) {
        ln_f32<<<SEQ, 256, 0, stream>>>(x, ln1_w + i * EMBED, ln1_b + i * EMBED, hbf, EMBED);
        transpose_cast<<<tgrid(QKVN, EMBED), tblk, 0, stream>>>(
            qkv_w + (size_t)i * EMBED * QKVN, wbuf, EMBED, QKVN, EMBED);
        gemm_bf16<0, 0, 0, 1><<<ggrid(SEQ, QKVN), 256, 0, stream>>>(
            hbf, wbuf, qkv_b + i * QKVN, qkvbuf, SEQ, QKVN, EMBED);
        rope_cast_qk<<<SEQ * HEADS * 48 / 256, 256, 0, stream>>>(qkvbuf, pos, qbv, kbv);
        v_transpose<<<HEADS * 80 * SEQ / 256, 256, 0, stream>>>(qkvbuf, vtb);
        attn_mfma<<<dim3(HEADS, NSEG, SEGLEN / 64), 256, 0, stream>>>(qbv, kbv, vtb, hbf);
        transpose_cast<<<tgrid(EMBED, EMBED), tblk, 0, stream>>>(
            proj_w + (size_t)i * EMBED * EMBED, wbuf, EMBED, EMBED, EMBED);
        gemm_bf16<0, 1, 0, 2><<<ggrid(SEQ, EMBED, 2), 256, 0, stream>>>(
            hbf, wbuf, proj_b + i * EMBED, x, SEQ, EMBED, EMBED);
        ln_f32<<<SEQ, 256, 0, stream>>>(x, ln2_w + i * EMBED, ln2_b + i * EMBED, hbf, EMBED);
        transpose_cast<<<tgrid(MLP, EMBED), tblk, 0, stream>>>(
            fc1_w + (size_t)i * EMBED * MLP, wbuf, EMBED, MLP, EMBED);
        gemm_bf16<1, 0, 1, 1><<<ggrid(SEQ, MLP), 256, 0, stream>>>(
            hbf, wbuf, fc1_b + i * MLP, fc1out, SEQ, MLP, EMBED);
        transpose_cast<<<tgrid(EMBED, MLP), tblk, 0, stream>>>(
            fc2_w + (size_t)i * MLP * EMBED, wbuf, MLP, EMBED, MLP);
        gemm_bf16<0, 1, 0, 4><<<ggrid(SEQ, EMBED, 4), 256, 0, stream>>>(
            fc1out, wbuf, fc2_b + i * EMBED, x, SEQ, EMBED, MLP);
    }

    // merger: mrg1 as split-K4 atomics into f32 partials, then gelu_cast
    ln_f32<<<SEQ, 256, 0, stream>>>(x, mln_w, mln_b, hbf, EMBED);
    transpose_cast<<<tgrid(HIDDEN, 4 * EMBED), tblk, 0, stream>>>(
        w1, wbuf, 4 * EMBED, HIDDEN, 4 * EMBED);
    hipMemsetAsync(mrg1f, 0, (size_t)MROWS * HIDDEN * 4, stream);
    gemm_bf16<0, 0, 0, 4><<<ggrid(MROWS, HIDDEN, 4), 256, 0, stream>>>(
        hbf, wbuf, b1, mrg1f, MROWS, HIDDEN, 4 * EMBED);
    gelu_cast<<<MROWS * HIDDEN / 1024, 256, 0, stream>>>(mrg1f, fc1out);
    transpose_cast<<<tgrid(HIDDEN, HIDDEN), tblk, 0, stream>>>(
        w2, wbuf, HIDDEN, HIDDEN, HIDDEN);
    // mrg2 via split-K atomics: zero out first
    hipMemsetAsync(out, 0, (size_t)MROWS * HIDDEN * 4, stream);
    gemm_bf16<0, 0, 0, 4><<<ggrid(MROWS, HIDDEN, 4), 256, 0, stream>>>(
        fc1out, wbuf, b2, out, MROWS, HIDDEN, HIDDEN);
}

// Round 9
// 778.942 us; speedup vs baseline: 14.3949x; 1.0084x over previous
//
#include <hip/hip_runtime.h>
#include <math.h>

#define SEQ    2048
#define EMBED  1280
#define HEADS  16
#define HD     80
#define MLP    5120
#define HIDDEN 3584
#define QKVN   3840
#define SEGLEN 1024
#define NSEG   2
#define PATCH_IN 1176
#define PATCH_KP 1280   // mult of 128 (split-2 -> klen 640)
#define MROWS  512

typedef __attribute__((ext_vector_type(8))) short bf16x8;
typedef __attribute__((ext_vector_type(4))) short s16x4;
typedef __attribute__((ext_vector_type(4))) float f32x4;
typedef unsigned short ushort_t;

__device__ __forceinline__ ushort_t f2bf(float f) {
    unsigned u = __builtin_bit_cast(unsigned, f);
    unsigned r = u + 0x7FFFu + ((u >> 16) & 1u);   // RNE
    return (ushort_t)(r >> 16);
}

__device__ __forceinline__ void gld_lds16(const void* g, void* l) {
    __builtin_amdgcn_global_load_lds(
        (const __attribute__((address_space(1))) void*)g,
        (__attribute__((address_space(3))) void*)l, 16, 0, 0);
}

// ---------------------------------------------------------------------------
// bf16 MFMA GEMM. r9: BK=32 double-buffered (32 KB LDS -> 5 blocks/CU,
// 20 waves/CU: 2.5x TLP vs r8's 64 KB / 2 blocks) with counted vmcnt(4).
// T2 XOR swizzle (4 slots, key row&3), T1 XCD swizzle, split-K atomics.
// ---------------------------------------------------------------------------
template<int EPI, int ACC, int OBF, int SPLIT>
__global__ __launch_bounds__(256) void gemm_bf16(
    const ushort_t* __restrict__ A, const ushort_t* __restrict__ Bt,
    const float* __restrict__ bias, void* __restrict__ Cout,
    int M, int N, int K)
{
    __shared__ __align__(16) short Abuf[2][128 * 32];
    __shared__ __align__(16) short Bbuf[2][128 * 32];

    const int tid  = threadIdx.x;
    const int lane = tid & 63, wid = tid >> 6;
    const int wr = wid >> 1, wc = wid & 1;

    // T1: XCD-aware bijective swizzle within each z-plane
    const int nwg  = gridDim.x * gridDim.y;
    const int flat = blockIdx.y * gridDim.x + blockIdx.x;
    int bx, by;
    if (nwg & 7) { bx = blockIdx.x; by = blockIdx.y; }
    else {
        const int swz = (flat & 7) * (nwg >> 3) + (flat >> 3);
        bx = swz % gridDim.x; by = swz / gridDim.x;
    }
    const int row0 = by * 128, col0 = bx * 128;
    const int kb = (SPLIT > 1) ? blockIdx.z * (K / SPLIT) : 0;
    const int klen = (SPLIT > 1) ? (K / SPLIT) : K;

    const int r0 = tid >> 2, s0 = tid & 3;      // staging row / 16B-slot (4 slots)
    const int lrow = lane & 15;
    const int lg = lane >> 4;
    const int rx = lrow & 3;                    // read-side swizzle key

    f32x4 acc[4][4] = {};

    auto stage = [&](int buf, int t) {
        const int k0 = kb + (t << 5);
        #pragma unroll
        for (int i = 0; i < 2; ++i) {
            const int r = r0 + i * 64;
            const int ksl = (s0 ^ (r & 3)) * 8;      // pre-swizzled source slot
            gld_lds16(A  + (size_t)(row0 + r) * K + k0 + ksl,
                      &Abuf[buf][(tid + i * 256) * 8]);
            gld_lds16(Bt + (size_t)(col0 + r) * K + k0 + ksl,
                      &Bbuf[buf][(tid + i * 256) * 8]);
        }
    };

    const int nt = klen >> 5;                    // klen mult of 64 -> nt even, >=20
    stage(0, 0);
    stage(1, 1);                                 // 8 loads in flight

    int cur = 0;
    for (int t = 0; t < nt; ++t) {
        // wait ONLY for buf[cur]'s 4 loads; keep the next 4 in flight
        if (t < nt - 1) { asm volatile("s_waitcnt vmcnt(4)" ::: "memory"); }
        else            { asm volatile("s_waitcnt vmcnt(0)" ::: "memory"); }
        __builtin_amdgcn_s_barrier();            // all waves' cur-loads landed

        bf16x8 a[4], b[4];
        const int ts = (lg ^ rx) * 8;            // swizzled read slot
        #pragma unroll
        for (int m = 0; m < 4; ++m)
            a[m] = *(const bf16x8*)&Abuf[cur][(wr * 64 + m * 16 + lrow) * 32 + ts];
        #pragma unroll
        for (int n = 0; n < 4; ++n)
            b[n] = *(const bf16x8*)&Bbuf[cur][(wc * 64 + n * 16 + lrow) * 32 + ts];
        asm volatile("s_waitcnt lgkmcnt(0)" ::: "memory");   // frags in regs
        __builtin_amdgcn_s_barrier();            // all waves done READING cur
        __builtin_amdgcn_sched_barrier(0);       // pin stage below the barrier

        if (t + 2 < nt) stage(cur, t + 2);       // overwrite cur for t+2

        #pragma unroll
        for (int m = 0; m < 4; ++m)
            #pragma unroll
            for (int n = 0; n < 4; ++n)
                acc[m][n] = __builtin_amdgcn_mfma_f32_16x16x32_bf16(
                    a[m], b[n], acc[m][n], 0, 0, 0);
        cur ^= 1;
    }

    // epilogue: C/D layout col = lane&15, row = (lane>>4)*4 + reg
    const int rbase = lg * 4;
    #pragma unroll
    for (int n = 0; n < 4; ++n) {
        const int c = col0 + wc * 64 + n * 16 + lrow;
        const float bv = bias ? bias[c] : 0.f;
        #pragma unroll
        for (int m = 0; m < 4; ++m) {
            const int rb = row0 + wr * 64 + m * 16 + rbase;
            #pragma unroll
            for (int g = 0; g < 4; ++g) {
                const size_t idx = (size_t)(rb + g) * N + c;
                if (SPLIT > 1) {
                    float v = acc[m][n][g] + (blockIdx.z == 0 ? bv : 0.f);
                    unsafeAtomicAdd(&((float*)Cout)[idx], v);
                } else {
                    float v = acc[m][n][g] + bv;
                    if (EPI == 1) v = v / (1.f + expf(-v));
                    if (EPI == 2) v = 0.5f * v * (1.f + erff(v * 0.70710678f));
                    if (OBF) {
                        ((ushort_t*)Cout)[idx] = f2bf(v);
                    } else {
                        float* Cf = (float*)Cout;
                        if (ACC) v += Cf[idx];
                        Cf[idx] = v;
                    }
                }
            }
        }
    }
}

// ---------------------------------------------------------------------------
// transpose + f32->bf16 cast (r8 version, 16B stores)
// ---------------------------------------------------------------------------
__global__ __launch_bounds__(256) void transpose_cast(
    const float* __restrict__ in, ushort_t* __restrict__ out, int K, int N, int Kp)
{
    __shared__ float t[32][33];
    const int n0 = blockIdx.x * 32, k0 = blockIdx.y * 32;
    const int tx = threadIdx.x, ty = threadIdx.y;   // 32 x 8
    #pragma unroll
    for (int j = 0; j < 4; ++j) {
        int k = k0 + ty + j * 8;
        t[ty + j * 8][tx] = (k < K) ? in[(size_t)k * N + n0 + tx] : 0.f;
    }
    __syncthreads();
    const int tid = ty * 32 + tx;
    if (tid < 128) {
        const int n = tid >> 2, kg = (tid & 3) * 8;
        bf16x8 v;
        #pragma unroll
        for (int j = 0; j < 8; ++j)
            v[j] = (short)f2bf(t[kg + j][n]);
        *(bf16x8*)&out[(size_t)(n0 + n) * Kp + k0 + kg] = v;
    }
}

__global__ __launch_bounds__(256) void cast_hs(
    const float* __restrict__ in, ushort_t* __restrict__ out)
{
    int idx = blockIdx.x * 256 + threadIdx.x;
    if (idx >= SEQ * PATCH_KP) return;
    int s = idx / PATCH_KP, k = idx % PATCH_KP;
    out[idx] = (k < PATCH_IN) ? f2bf(in[(size_t)s * PATCH_IN + k]) : 0;
}

// gelu epilogue for split-K mrg1
__global__ __launch_bounds__(256) void gelu_cast(
    const float* __restrict__ in, ushort_t* __restrict__ out)
{
    const int idx = blockIdx.x * 256 + threadIdx.x;
    f32x4 v = ((const f32x4*)in)[idx];
    s16x4 r;
    #pragma unroll
    for (int j = 0; j < 4; ++j)
        r[j] = (short)f2bf(0.5f * v[j] * (1.f + erff(v[j] * 0.70710678f)));
    *(s16x4*)&out[idx * 4] = r;
}

// ---------------------------------------------------------------------------
// LayerNorm (unchanged)
// ---------------------------------------------------------------------------
__global__ __launch_bounds__(256) void ln_f32(
    const float* __restrict__ x, const float* __restrict__ w,
    const float* __restrict__ b, ushort_t* __restrict__ y, int D)
{
    const int row = blockIdx.x;
    const float* xr = x + (size_t)row * D;
    float s = 0.f, ss = 0.f;
    for (int d = threadIdx.x; d < D; d += 256) {
        float v = xr[d];
        s += v; ss = fmaf(v, v, ss);
    }
    __shared__ float red[2][4];
    const int lane = threadIdx.x & 63, wid = threadIdx.x >> 6;
    #pragma unroll
    for (int off = 32; off; off >>= 1) {
        s  += __shfl_xor(s,  off);
        ss += __shfl_xor(ss, off);
    }
    if (lane == 0) { red[0][wid] = s; red[1][wid] = ss; }
    __syncthreads();
    s  = red[0][0] + red[0][1] + red[0][2] + red[0][3];
    ss = red[1][0] + red[1][1] + red[1][2] + red[1][3];
    const float mu  = s / D;
    const float var = ss / D - mu * mu;
    const float inv = rsqrtf(var + 1e-6f);
    ushort_t* yr = y + (size_t)row * D;
    for (int d = threadIdx.x; d < D; d += 256)
        yr[d] = f2bf((xr[d] - mu) * inv * w[d] + b[d]);
}

// ---------------------------------------------------------------------------
// RoPE + scale + bf16 cast + head-major relayout (unchanged)
// ---------------------------------------------------------------------------
__global__ __launch_bounds__(256) void rope_cast_qk(
    const float* __restrict__ qkv, const int* __restrict__ pos,
    ushort_t* __restrict__ qb, ushort_t* __restrict__ kb)
{
    int idx = blockIdx.x * 256 + threadIdx.x;
    const int j = idx % 48;
    const int h = (idx / 48) % HEADS;
    const int s = idx / (48 * HEADS);
    if (s >= SEQ) return;
    const size_t ob = ((size_t)h * SEQ + s) * 96;
    if (j >= 40) {
        qb[ob + 40 + j] = 0; qb[ob + 48 + j] = 0;
        kb[ob + 40 + j] = 0; kb[ob + 48 + j] = 0;
        return;
    }
    const float p = (float)pos[s * 2 + (j / 20)];
    const float f = p * powf(10000.f, -(float)(j % 20) / 20.f);
    float c, sn;
    sincosf(f, &c, &sn);
    const float* q = qkv + (size_t)s * QKVN + h * HD;
    const float* k = q + EMBED;
    const float scale = 0.11180339887498949f;
    float q1 = q[j], q2 = q[j + 40];
    qb[ob + j]      = f2bf((q1 * c - q2 * sn) * scale);
    qb[ob + j + 40] = f2bf((q2 * c + q1 * sn) * scale);
    float k1 = k[j], k2 = k[j + 40];
    kb[ob + j]      = f2bf(k1 * c - k2 * sn);
    kb[ob + j + 40] = f2bf(k2 * c + k1 * sn);
}

// ---------------------------------------------------------------------------
// V transpose, r9: LDS-tiled (old version read at 15 KB lane stride -> 16x
// overfetch). Coalesced 320B reads along d; 16B stores along s.
// grid (SEQ/32, HEADS), block (80,4).
// ---------------------------------------------------------------------------
__global__ __launch_bounds__(320) void v_transpose(
    const float* __restrict__ qkv, ushort_t* __restrict__ vtb)
{
    __shared__ float t[32][81];
    const int sb = blockIdx.x * 32, h = blockIdx.y;
    const int tx = threadIdx.x, ty = threadIdx.y;      // 80 x 4
    #pragma unroll
    for (int i = 0; i < 8; ++i) {
        const int s = ty * 8 + i;
        t[s][tx] = qkv[(size_t)(sb + s) * QKVN + 2 * EMBED + h * HD + tx];
    }
    __syncthreads();
    const int tid = ty * 80 + tx;
    const int d = tid >> 2, s0 = (tid & 3) * 8;
    bf16x8 v;
    #pragma unroll
    for (int j = 0; j < 8; ++j)
        v[j] = (short)f2bf(t[s0 + j][d]);
    *(bf16x8*)&vtb[((size_t)h * 80 + d) * SEQ + sb + s0] = v;
}

// ---------------------------------------------------------------------------
// MFMA flash attention (unchanged)
// ---------------------------------------------------------------------------
#define AKC  64
#define KSTR 104
#define VSTR 72
#define PSTR 72

__global__ __launch_bounds__(256) void attn_mfma(
    const ushort_t* __restrict__ qb, const ushort_t* __restrict__ kb,
    const ushort_t* __restrict__ vtb, ushort_t* __restrict__ out)
{
    const int hh = blockIdx.x;
    const int seg = blockIdx.y;
    const int tid = threadIdx.x, lane = tid & 63, wid = tid >> 6;
    const int lr = lane & 15, lg = lane >> 4;

    __shared__ __align__(16) short Ks[AKC * KSTR];
    __shared__ __align__(16) short Vs[80 * VSTR];
    __shared__ __align__(16) short Ps[4][16 * PSTR];

    const int sq = seg * SEGLEN;
    const int qrow0 = sq + blockIdx.z * 64 + wid * 16;

    bf16x8 qf[3];
    #pragma unroll
    for (int f = 0; f < 3; ++f)
        qf[f] = *(const bf16x8*)&qb[((size_t)hh * SEQ + qrow0 + lr) * 96 + f * 32 + lg * 8];

    f32x4 o[5] = {};
    float m[4], l[4];
    #pragma unroll
    for (int g = 0; g < 4; ++g) { m[g] = -1e30f; l[g] = 0.f; }

    for (int c0 = 0; c0 < SEGLEN; c0 += AKC) {
        __syncthreads();
        #pragma unroll
        for (int i = 0; i < 3; ++i) {
            int id = tid + i * 256;
            int r = id / 12, s = id % 12;
            *(bf16x8*)&Ks[r * KSTR + s * 8] =
                *(const bf16x8*)&kb[((size_t)hh * SEQ + sq + c0 + r) * 96 + s * 8];
        }
        #pragma unroll
        for (int i = 0; i < 3; ++i) {
            int id = tid + i * 256;
            if (id < 640) {
                int d = id / 8, s = id % 8;
                *(bf16x8*)&Vs[d * VSTR + s * 8] =
                    *(const bf16x8*)&vtb[((size_t)hh * 80 + d) * SEQ + sq + c0 + s * 8];
            }
        }
        __syncthreads();

        f32x4 sc[4] = {};
        #pragma unroll
        for (int kt = 0; kt < 4; ++kt)
            #pragma unroll
            for (int f = 0; f < 3; ++f) {
                bf16x8 kf = *(const bf16x8*)&Ks[(kt * 16 + lr) * KSTR + f * 32 + lg * 8];
                sc[kt] = __builtin_amdgcn_mfma_f32_16x16x32_bf16(qf[f], kf, sc[kt], 0, 0, 0);
            }

        float corr[4], ps[4];
        #pragma unroll
        for (int g = 0; g < 4; ++g) {
            float v = fmaxf(fmaxf(sc[0][g], sc[1][g]), fmaxf(sc[2][g], sc[3][g]));
            v = fmaxf(v, __shfl_xor(v, 1));
            v = fmaxf(v, __shfl_xor(v, 2));
            v = fmaxf(v, __shfl_xor(v, 4));
            v = fmaxf(v, __shfl_xor(v, 8));
            const float mn = fmaxf(m[g], v);
            corr[g] = __expf(m[g] - mn);
            m[g] = mn;
            ps[g] = 0.f;
        }
        #pragma unroll
        for (int kt = 0; kt < 4; ++kt)
            #pragma unroll
            for (int g = 0; g < 4; ++g) {
                float p = __expf(sc[kt][g] - m[g]);
                ps[g] += p;
                Ps[wid][(lg * 4 + g) * PSTR + kt * 16 + lr] = f2bf(p);
            }
        #pragma unroll
        for (int g = 0; g < 4; ++g) {
            float rs = ps[g];
            rs += __shfl_xor(rs, 1);
            rs += __shfl_xor(rs, 2);
            rs += __shfl_xor(rs, 4);
            rs += __shfl_xor(rs, 8);
            l[g] = l[g] * corr[g] + rs;
        }
        #pragma unroll
        for (int n = 0; n < 5; ++n)
            #pragma unroll
            for (int g = 0; g < 4; ++g) o[n][g] *= corr[g];

        #pragma unroll
        for (int jf = 0; jf < 2; ++jf) {
            bf16x8 pa = *(const bf16x8*)&Ps[wid][lr * PSTR + jf * 32 + lg * 8];
            #pragma unroll
            for (int n = 0; n < 5; ++n) {
                bf16x8 vf = *(const bf16x8*)&Vs[(n * 16 + lr) * VSTR + jf * 32 + lg * 8];
                o[n] = __builtin_amdgcn_mfma_f32_16x16x32_bf16(pa, vf, o[n], 0, 0, 0);
            }
        }
    }

    #pragma unroll
    for (int g = 0; g < 4; ++g) {
        const float inv = 1.f / l[g];
        const int r = qrow0 + lg * 4 + g;
        #pragma unroll
        for (int n = 0; n < 5; ++n)
            out[(size_t)r * EMBED + hh * HD + n * 16 + lr] = f2bf(o[n][g] * inv);
    }
}

// ---------------------------------------------------------------------------

extern "C" void kernel_launch(void* const* d_in, const int* in_sizes, int n_in,
                              void* d_out, int out_size, void* d_ws, size_t ws_size,
                              hipStream_t stream)
{
    const float* hs      = (const float*)d_in[0];
    const int*   pos     = (const int*)  d_in[1];
    const float* patch_w = (const float*)d_in[3];
    const float* ln1_w   = (const float*)d_in[4];
    const float* ln1_b   = (const float*)d_in[5];
    const float* ln2_w   = (const float*)d_in[6];
    const float* ln2_b   = (const float*)d_in[7];
    const float* qkv_w   = (const float*)d_in[8];
    const float* qkv_b   = (const float*)d_in[9];
    const float* proj_w  = (const float*)d_in[10];
    const float* proj_b  = (const float*)d_in[11];
    const float* fc1_w   = (const float*)d_in[12];
    const float* fc1_b   = (const float*)d_in[13];
    const float* fc2_w   = (const float*)d_in[14];
    const float* fc2_b   = (const float*)d_in[15];
    const float* mln_w   = (const float*)d_in[16];
    const float* mln_b   = (const float*)d_in[17];
    const float* w1      = (const float*)d_in[18];
    const float* b1      = (const float*)d_in[19];
    const float* w2      = (const float*)d_in[20];
    const float* b2      = (const float*)d_in[21];
    float* out = (float*)d_out;

    char* p = (char*)d_ws;
    float*    x      = (float*)p;            p += (size_t)SEQ * EMBED * 4;
    float*    qkvbuf = (float*)p;            p += (size_t)SEQ * QKVN * 4;
    ushort_t* hbf    = (ushort_t*)p;         p += (size_t)SEQ * EMBED * 2;
    ushort_t* hsbf   = (ushort_t*)p;         p += (size_t)SEQ * PATCH_KP * 2;
    ushort_t* wbuf   = (ushort_t*)p;
    ushort_t* fc1out = (ushort_t*)qkvbuf;
    float*    mrg1f  = (float*)((char*)qkvbuf + (8 << 20));
    ushort_t* qbv = wbuf;
    ushort_t* kbv = qbv + (size_t)HEADS * SEQ * 96;
    ushort_t* vtb = kbv + (size_t)HEADS * SEQ * 96;

    const dim3 tblk(32, 8);
    auto tgrid = [](int N, int Kp) { return dim3(N / 32, Kp / 32); };
    auto ggrid = [](int M, int N, int S = 1) { return dim3(N / 128, M / 128, S); };

    cast_hs<<<(SEQ * PATCH_KP + 255) / 256, 256, 0, stream>>>(hs, hsbf);
    transpose_cast<<<tgrid(EMBED, PATCH_KP), tblk, 0, stream>>>(
        patch_w, wbuf, PATCH_IN, EMBED, PATCH_KP);
    hipMemsetAsync(x, 0, (size_t)SEQ * EMBED * 4, stream);
    gemm_bf16<0, 0, 0, 2><<<ggrid(SEQ, EMBED, 2), 256, 0, stream>>>(
        hsbf, wbuf, nullptr, x, SEQ, EMBED, PATCH_KP);

    for (int i = 0; i < 2; ++i) {
        ln_f32<<<SEQ, 256, 0, stream>>>(x, ln1_w + i * EMBED, ln1_b + i * EMBED, hbf, EMBED);
        transpose_cast<<<tgrid(QKVN, EMBED), tblk, 0, stream>>>(
            qkv_w + (size_t)i * EMBED * QKVN, wbuf, EMBED, QKVN, EMBED);
        gemm_bf16<0, 0, 0, 1><<<ggrid(SEQ, QKVN), 256, 0, stream>>>(
            hbf, wbuf, qkv_b + i * QKVN, qkvbuf, SEQ, QKVN, EMBED);
        rope_cast_qk<<<SEQ * HEADS * 48 / 256, 256, 0, stream>>>(qkvbuf, pos, qbv, kbv);
        v_transpose<<<dim3(SEQ / 32, HEADS), dim3(80, 4), 0, stream>>>(qkvbuf, vtb);
        attn_mfma<<<dim3(HEADS, NSEG, SEGLEN / 64), 256, 0, stream>>>(qbv, kbv, vtb, hbf);
        transpose_cast<<<tgrid(EMBED, EMBED), tblk, 0, stream>>>(
            proj_w + (size_t)i * EMBED * EMBED, wbuf, EMBED, EMBED, EMBED);
        gemm_bf16<0, 1, 0, 2><<<ggrid(SEQ, EMBED, 2), 256, 0, stream>>>(
            hbf, wbuf, proj_b + i * EMBED, x, SEQ, EMBED, EMBED);
        ln_f32<<<SEQ, 256, 0, stream>>>(x, ln2_w + i * EMBED, ln2_b + i * EMBED, hbf, EMBED);
        transpose_cast<<<tgrid(MLP, EMBED), tblk, 0, stream>>>(
            fc1_w + (size_t)i * EMBED * MLP, wbuf, EMBED, MLP, EMBED);
        gemm_bf16<1, 0, 1, 1><<<ggrid(SEQ, MLP), 256, 0, stream>>>(
            hbf, wbuf, fc1_b + i * MLP, fc1out, SEQ, MLP, EMBED);
        transpose_cast<<<tgrid(EMBED, MLP), tblk, 0, stream>>>(
            fc2_w + (size_t)i * MLP * EMBED, wbuf, MLP, EMBED, MLP);
        gemm_bf16<0, 1, 0, 4><<<ggrid(SEQ, EMBED, 4), 256, 0, stream>>>(
            fc1out, wbuf, fc2_b + i * EMBED, x, SEQ, EMBED, MLP);
    }

    // merger
    ln_f32<<<SEQ, 256, 0, stream>>>(x, mln_w, mln_b, hbf, EMBED);
    transpose_cast<<<tgrid(HIDDEN, 4 * EMBED), tblk, 0, stream>>>(
        w1, wbuf, 4 * EMBED, HIDDEN, 4 * EMBED);
    hipMemsetAsync(mrg1f, 0, (size_t)MROWS * HIDDEN * 4, stream);
    gemm_bf16<0, 0, 0, 4><<<ggrid(MROWS, HIDDEN, 4), 256, 0, stream>>>(
        hbf, wbuf, b1, mrg1f, MROWS, HIDDEN, 4 * EMBED);
    gelu_cast<<<MROWS * HIDDEN / 1024, 256, 0, stream>>>(mrg1f, fc1out);
    transpose_cast<<<tgrid(HIDDEN, HIDDEN), tblk, 0, stream>>>(
        w2, wbuf, HIDDEN, HIDDEN, HIDDEN);
    hipMemsetAsync(out, 0, (size_t)MROWS * HIDDEN * 4, stream);
    gemm_bf16<0, 0, 0, 4><<<ggrid(MROWS, HIDDEN, 4), 256, 0, stream>>>(
        fc1out, wbuf, b2, out, MROWS, HIDDEN, HIDDEN);
}